// Round 12
// baseline (305.088 us; speedup 1.0000x reference)
//
#include <hip/hip_runtime.h>
#include <cstdint>
#include <cstddef>

constexpr int B = 8, S = 4096, D = 512, R = 16;
constexpr int M = B * S;                         // 32768 rows
constexpr long long OUT_ELEMS = (long long)M * 3 * D;  // 50331648

typedef short short8 __attribute__((ext_vector_type(8)));
typedef float f32x4 __attribute__((ext_vector_type(4)));

__device__ __forceinline__ ushort f2bf(float f) {
    union { float f; unsigned u; } v; v.f = f;
    return (ushort)((v.u + 0x7fffu + ((v.u >> 16) & 1u)) >> 16);
}

__device__ __forceinline__ void gload_lds16(const void* g, void* l) {
    __builtin_amdgcn_global_load_lds(
        (const __attribute__((address_space(1))) void*)g,
        (__attribute__((address_space(3))) void*)l, 16, 0, 0);
}

// ---------------- occ + fused copy: w-in-registers, zero x reload -----------
// 1024 blocks x 4 waves x 8 rows.  Once per wave: lane loads its contiguous
// 512B w-slice occ_w[lane*8 .. lane*8+8)[0..16) into 32 f32x4 (128 VGPR).
// Per row: phase 1 = coalesced copy (x->out.x, g->out.g, x->xb); the SAME
// registers feed phase 2: 128 static fp64 FMAs -> 16 partial logits; a
// 4-step reduce-scatter (fp64 shuffles, LDS pipe) lands the 64-lane total
// for logit r=lane&15 in each lane; then the r7/r8-proven finale (2 xor-adds,
// first-occurrence argmax butterfly, expf sum).  Per-row VMEM: 4 loads +
// 5 stores (was 160+).  No barriers anywhere.
__global__ __launch_bounds__(256, 2) void occ_kernel(
    const float* __restrict__ x, const float* __restrict__ occ_w,
    const float* __restrict__ occ_b, const float* __restrict__ g_vec,
    int* __restrict__ reg_indx, float* __restrict__ reg_logit,
    ushort* __restrict__ xb, float* __restrict__ out, int writeOut)
{
    const int wave = threadIdx.x >> 6, lane = threadIdx.x & 63;
    const int r16 = lane & 15;
    f32x4 wreg[32];                       // wreg[j*4+q][t] = w[(lane*8+j)*16+q*4+t]
    {
        const f32x4* wsrc = (const f32x4*)(occ_w + (size_t)lane * 128);
#pragma unroll
        for (int i = 0; i < 32; ++i) wreg[i] = wsrc[i];
    }
    const double bias = (double)occ_b[r16];
    const int row0 = blockIdx.x * 32 + wave * 8;
#pragma unroll 1
    for (int rr = 0; rr < 8; ++rr) {
        const int row = row0 + rr;
        const float4* xrow4 = (const float4*)(x + (size_t)row * D);
        const float4 c0 = xrow4[lane * 2], c1 = xrow4[lane * 2 + 1];
        // ---- phase 1: coalesced copy ----
        short8 pk;
        pk[0] = (short)f2bf(c0.x); pk[1] = (short)f2bf(c0.y);
        pk[2] = (short)f2bf(c0.z); pk[3] = (short)f2bf(c0.w);
        pk[4] = (short)f2bf(c1.x); pk[5] = (short)f2bf(c1.y);
        pk[6] = (short)f2bf(c1.z); pk[7] = (short)f2bf(c1.w);
        *(short8*)&xb[(size_t)row * D + lane * 8] = pk;
        if (writeOut) {
            float* orow = out + (size_t)row * 3 * D;
            ((float4*)orow)[lane * 2]     = c0;
            ((float4*)orow)[lane * 2 + 1] = c1;
            const float4* gr4 = (const float4*)(g_vec + (size_t)(row >> 12) * D);
            ((float4*)(orow + 2 * D))[lane * 2]     = gr4[lane * 2];
            ((float4*)(orow + 2 * D))[lane * 2 + 1] = gr4[lane * 2 + 1];
        }
        // ---- phase 2: 16 fp64 partials from registers ----
        const float xs[8] = {c0.x, c0.y, c0.z, c0.w, c1.x, c1.y, c1.z, c1.w};
        double v[16];
#pragma unroll
        for (int i = 0; i < 16; ++i) v[i] = 0.0;
#pragma unroll
        for (int j = 0; j < 8; ++j) {
            const double xd = (double)xs[j];
#pragma unroll
            for (int q = 0; q < 4; ++q) {
                const f32x4 wv = wreg[j * 4 + q];
                v[q * 4 + 0] += xd * (double)wv[0];
                v[q * 4 + 1] += xd * (double)wv[1];
                v[q * 4 + 2] += xd * (double)wv[2];
                v[q * 4 + 3] += xd * (double)wv[3];
            }
        }
        // ---- reduce-scatter: lane ends with 16-lane-group sum for r16 ----
        double t8[8];
#pragma unroll
        for (int i = 0; i < 8; ++i) {
            const double lo = __shfl_xor(v[i], 8, 64);
            const double hi = __shfl_xor(v[i + 8], 8, 64);
            t8[i] = (lane & 8) ? (v[i + 8] + hi) : (v[i] + lo);
        }
        double t4[4];
#pragma unroll
        for (int i = 0; i < 4; ++i) {
            const double lo = __shfl_xor(t8[i], 4, 64);
            const double hi = __shfl_xor(t8[i + 4], 4, 64);
            t4[i] = (lane & 4) ? (t8[i + 4] + hi) : (t8[i] + lo);
        }
        double t2[2];
#pragma unroll
        for (int i = 0; i < 2; ++i) {
            const double lo = __shfl_xor(t4[i], 2, 64);
            const double hi = __shfl_xor(t4[i + 2], 2, 64);
            t2[i] = (lane & 2) ? (t4[i + 2] + hi) : (t4[i] + lo);
        }
        double s;
        {
            const double lo = __shfl_xor(t2[0], 1, 64);
            const double hi = __shfl_xor(t2[1], 1, 64);
            s = (lane & 1) ? (t2[1] + hi) : (t2[0] + lo);
        }
        s += __shfl_xor(s, 16, 64);
        s += __shfl_xor(s, 32, 64);
        s += bias;                                // lane's logit, r = lane&15
        // ---- r7/r8-proven finale ----
        double mv = s; int mi = r16;
#pragma unroll
        for (int off = 1; off < 16; off <<= 1) {
            const double ov = __shfl_xor(mv, off, 64);
            const int    oi = __shfl_xor(mi, off, 64);
            if (ov > mv || (ov == mv && oi < mi)) { mv = ov; mi = oi; }
        }
        float ef = expf((float)(s - mv));
#pragma unroll
        for (int off = 1; off < 16; off <<= 1) ef += __shfl_xor(ef, off, 64);
        if (lane == 0) { reg_indx[row] = mi; reg_logit[row] = 1.0f / ef; }
    }
}

// ---------------- wtrans: w1/w2 transpose + bf16 convert --------------------
__global__ __launch_bounds__(256) void wtrans_kernel(
    const float* __restrict__ w1, const float* __restrict__ w2,
    ushort* __restrict__ w1t, ushort* __restrict__ w2t)
{
    __shared__ float tile[32][33];
    const int tid = threadIdx.x;
    const int wb = blockIdx.x;                    // 0..511
    const float* w = (wb >> 8) ? w2 : w1;
    ushort* wt = (wb >> 8) ? w2t : w1t;
    const int rest = wb & 255;
    const int n0 = (rest & 15) * 32, k0 = (rest >> 4) * 32;
    const int tx = tid & 31, ty = tid >> 5;
#pragma unroll
    for (int qq = 0; qq < 4; ++qq)
        tile[ty * 4 + qq][tx] = w[(size_t)(k0 + ty * 4 + qq) * D + n0 + tx];
    __syncthreads();
#pragma unroll
    for (int qq = 0; qq < 4; ++qq)
        wt[(size_t)(n0 + ty * 4 + qq) * D + k0 + tx] = f2bf(tile[tx][ty * 4 + qq]);
}

// ---------------- loss partials: 64 blocks = (batch, chunk-of-512-rows) ----
__global__ __launch_bounds__(256) void loss_part_kernel(
    const int* __restrict__ reg_indx, const float* __restrict__ reg_logit,
    int* __restrict__ pcnt, double* __restrict__ psum)
{
    const int b = blockIdx.x >> 3, c = blockIdx.x & 7;
    const int t = threadIdx.x;
    __shared__ double ssum[R][257];
    __shared__ int    scnt[R][257];
#pragma unroll
    for (int r = 0; r < R; ++r) { ssum[r][t] = 0.0; scnt[r][t] = 0; }
    __syncthreads();
    const int base = b * S + c * 512;
    for (int s = t; s < 512; s += 256) {
        const int r = reg_indx[base + s];
        ssum[r][t] += (double)reg_logit[base + s];
        scnt[r][t] += 1;
    }
    __syncthreads();
    for (int off = 128; off > 0; off >>= 1) {
        if (t < off) {
#pragma unroll
            for (int r = 0; r < R; ++r) {
                ssum[r][t] += ssum[r][t + off];
                scnt[r][t] += scnt[r][t + off];
            }
        }
        __syncthreads();
    }
    if (t < R) {
        psum[blockIdx.x * R + t] = ssum[t][0];
        pcnt[blockIdx.x * R + t] = scnt[t][0];
    }
}

// ---------------- loss final: combine partials, emit counts + scalar loss ---
__global__ void loss_final_kernel(const int* __restrict__ pcnt,
                                  const double* __restrict__ psum,
                                  int* __restrict__ counts,
                                  float* __restrict__ out_loss)
{
    __shared__ double m2[128];
    const int t = threadIdx.x;            // 128 threads = (b,r)
    const int b = t >> 4, r = t & 15;
    int cnt = 0; double s = 0.0;
#pragma unroll
    for (int c = 0; c < 8; ++c) {
        cnt += pcnt[(b * 8 + c) * R + r];
        s   += psum[(b * 8 + c) * R + r];
    }
    counts[b * R + r] = cnt;
    const double mean = s / (double)S;
    m2[t] = mean * mean;
    __syncthreads();
    if (t == 0) {
        double tot = 0.0;
        for (int i = 0; i < 128; ++i) tot += m2[i];
        *out_loss = (float)(tot / (double)B);
    }
}

// ---------------- fused c2 compute + regvec init, 16 blocks ------------------
__global__ __launch_bounds__(256) void init_regvec_c2_kernel(
    const float* __restrict__ b1, const float* __restrict__ w2,
    const float* __restrict__ b2, const int* __restrict__ counts,
    float* __restrict__ regvec)
{
    __shared__ float c1[D];
    __shared__ float part[8][33];
    const int t = threadIdx.x;
    c1[t]       = fmaxf(b1[t], 0.f);
    c1[t + 256] = fmaxf(b1[t + 256], 0.f);
    __syncthreads();
    const int dl = t & 31, kg = t >> 5;        // 8 k-groups x 64 k
    const int d = blockIdx.x * 32 + dl;
    float p = 0.f;
    for (int k = kg * 64; k < kg * 64 + 64; ++k)
        p += c1[k] * w2[(size_t)k * D + d];
    part[kg][dl] = p;
    __syncthreads();
    if (t < 32) {
        const int dd = blockIdx.x * 32 + t;
        float acc = b2[dd];
#pragma unroll
        for (int kk = 0; kk < 8; ++kk) acc += part[kk][t];
        const float c2d = fmaxf(acc, 0.f);
        for (int br = 0; br < B * R; ++br)
            regvec[(size_t)br * D + dd] = (counts[br] < S) ? c2d : 0.f;
    }
}

// ================= MFMA GEMM: 128x128 tile, 4 waves, 16x16x32 bf16 ==========
struct GemmCtx {
    int row0, col0, wave, lane, wr, wc;
    unsigned dsto[2];
    const ushort *aSrc[2], *bSrc[2];
    unsigned aOff[4], bOff[4];
};

__device__ __forceinline__ void gemm_setup(
    GemmCtx& c, const ushort* Ab, const ushort* Bt)
{
    const int tid = threadIdx.x;
    c.wave = tid >> 6; c.lane = tid & 63;
    c.wr = c.wave >> 1; c.wc = c.wave & 1;
    // bijective XCD swizzle over nwg=1024 (8 XCDs x 128 chunks)
    const int orig = blockIdx.x;
    const int wg = (orig & 7) * 128 + (orig >> 3);
    c.row0 = (wg >> 2) * 128;   // 256 mtiles
    c.col0 = (wg & 3) * 128;    // 4 ntiles
#pragma unroll
    for (int q = 0; q < 2; ++q) {
        const unsigned o = (unsigned)(c.wave * 2 + q) * 1024u + (unsigned)c.lane * 16u;
        c.dsto[q] = (unsigned)(c.wave * 2 + q) * 1024u;
        const unsigned r  = ((o >> 7) << 1) | (((o >> 6) ^ (o >> 8)) & 1u);
        const unsigned kg = ((o >> 4) & 3u) ^ (r & 3u);
        c.aSrc[q] = Ab + (size_t)(c.row0 + r) * D + kg * 8;
        c.bSrc[q] = Bt + (size_t)(c.col0 + r) * D + kg * 8;
    }
#pragma unroll
    for (int i = 0; i < 4; ++i) {
        const unsigned kg = (unsigned)(c.lane >> 4);
        unsigned r = (unsigned)(c.wr * 64 + i * 16 + (c.lane & 15));
        c.aOff[i] = ((r << 6) + (kg << 4)) ^ ((r & 7u) << 4);
        r = (unsigned)(c.wc * 64 + i * 16 + (c.lane & 15));
        c.bOff[i] = ((r << 6) + (kg << 4)) ^ ((r & 7u) << 4);
    }
}

#define STAGE4(ctx, smA, smB, bufofs, kt)                                 \
    gload_lds16(ctx.aSrc[0] + (kt), smA + (bufofs) + ctx.dsto[0]);        \
    gload_lds16(ctx.aSrc[1] + (kt), smA + (bufofs) + ctx.dsto[1]);        \
    gload_lds16(ctx.bSrc[0] + (kt), smB + (bufofs) + ctx.dsto[0]);        \
    gload_lds16(ctx.bSrc[1] + (kt), smB + (bufofs) + ctx.dsto[1]);

#define GEMM_KLOOP(smA, smB, ctx, acc)                                         \
    STAGE4(ctx, smA, smB, 0, 0)                                                \
    __syncthreads();                                                           \
    _Pragma("unroll")                                                          \
    for (int t = 0; t < 16; ++t) {                                             \
        const int co = (t & 1) * 8192;                                         \
        if (t < 15) { STAGE4(ctx, smA, smB, co ^ 8192, (t + 1) * 32) }         \
        short8 a[4], b[4];                                                     \
        _Pragma("unroll")                                                      \
        for (int i = 0; i < 4; ++i)                                            \
            a[i] = *(const short8*)(smA + co + ctx.aOff[i]);                   \
        _Pragma("unroll")                                                      \
        for (int j = 0; j < 4; ++j)                                            \
            b[j] = *(const short8*)(smB + co + ctx.bOff[j]);                   \
        _Pragma("unroll")                                                      \
        for (int i = 0; i < 4; ++i)                                            \
            _Pragma("unroll")                                                  \
            for (int j = 0; j < 4; ++j)                                        \
                acc[i][j] = __builtin_amdgcn_mfma_f32_16x16x32_bf16(           \
                    a[i], b[j], acc[i][j], 0, 0, 0);                           \
        __syncthreads();                                                       \
    }

// GEMM1: h1 = relu(xb @ w1t^T + b1), bf16 out
__global__ __launch_bounds__(256, 2) void gemm_mfma1(
    const ushort* __restrict__ Ab, const ushort* __restrict__ Bt,
    const float* __restrict__ bias, ushort* __restrict__ H)
{
    __shared__ ushort As[8192];
    __shared__ ushort Bs[8192];
    GemmCtx c; gemm_setup(c, Ab, Bt);
    char* smA = (char*)As; char* smB = (char*)Bs;
    f32x4 acc[4][4];
#pragma unroll
    for (int i = 0; i < 4; ++i)
#pragma unroll
        for (int j = 0; j < 4; ++j) acc[i][j] = (f32x4)0.f;
    GEMM_KLOOP(smA, smB, c, acc)
    float bb[4];
#pragma unroll
    for (int j = 0; j < 4; ++j) bb[j] = bias[c.col0 + c.wc * 64 + j * 16 + (c.lane & 15)];
#pragma unroll
    for (int i = 0; i < 4; ++i) {
        const int row = c.row0 + c.wr * 64 + i * 16 + ((c.lane >> 4) << 2);
#pragma unroll
        for (int j = 0; j < 4; ++j) {
            const int col = c.col0 + c.wc * 64 + j * 16 + (c.lane & 15);
#pragma unroll
            for (int ii = 0; ii < 4; ++ii) {
                const float v = fmaxf(acc[i][j][ii] + bb[j], 0.f);
                H[(size_t)(row + ii) * D + col] = f2bf(v);
            }
        }
    }
}

// GEMM2: v = relu(h1 @ w2t^T + b2); segmented max by reg_indx into regvec
__global__ __launch_bounds__(256, 2) void gemm_mfma2(
    const ushort* __restrict__ Ab, const ushort* __restrict__ Bt,
    const float* __restrict__ bias, const int* __restrict__ reg_indx,
    float* __restrict__ regvec)
{
    __shared__ ushort As[8192];
    __shared__ ushort Bs[8192];
    __shared__ unsigned redmax[R * 128];
    __shared__ int rowreg[128];
    GemmCtx c; gemm_setup(c, Ab, Bt);
    char* smA = (char*)As; char* smB = (char*)Bs;
    const int tid = threadIdx.x;
    if (tid < 128) rowreg[tid] = reg_indx[c.row0 + tid];
#pragma unroll
    for (int q = 0; q < 8; ++q) redmax[tid + q * 256] = 0u;
    f32x4 acc[4][4];
#pragma unroll
    for (int i = 0; i < 4; ++i)
#pragma unroll
        for (int j = 0; j < 4; ++j) acc[i][j] = (f32x4)0.f;
    GEMM_KLOOP(smA, smB, c, acc)   // barriers inside make the init visible
    float bb[4];
#pragma unroll
    for (int j = 0; j < 4; ++j) bb[j] = bias[c.col0 + c.wc * 64 + j * 16 + (c.lane & 15)];
#pragma unroll
    for (int i = 0; i < 4; ++i) {
        const int lrow = c.wr * 64 + i * 16 + ((c.lane >> 4) << 2);
#pragma unroll
        for (int j = 0; j < 4; ++j) {
            const int lcol = c.wc * 64 + j * 16 + (c.lane & 15);
#pragma unroll
            for (int ii = 0; ii < 4; ++ii) {
                const float v = fmaxf(acc[i][j][ii] + bb[j], 0.f);
                atomicMax(&redmax[rowreg[lrow + ii] * 128 + lcol], __float_as_uint(v));
            }
        }
    }
    __syncthreads();
    const int b = c.row0 >> 12;
#pragma unroll
    for (int q = 0; q < 8; ++q) {
        const int idx = tid + q * 256;
        const int r = idx >> 7, col = idx & 127;
        atomicMax((unsigned*)&regvec[(((size_t)b * R + r) << 9) + c.col0 + col],
                  redmax[idx]);
    }
}

// ---------------- output: middle slice only (x/g written by occ) ------------
__global__ __launch_bounds__(256) void out_mid_kernel(
    const float* __restrict__ regvec, const int* __restrict__ reg_indx,
    float* __restrict__ out)
{
    const int row = blockIdx.x * 2 + (threadIdx.x >> 7);
    const int t = threadIdx.x & 127;
    const int b = row >> 12;
    const int r = reg_indx[row];
    const float4* rv = (const float4*)(regvec + ((size_t)b * R + r) * D);
    float4* o = (float4*)(out + (size_t)row * 3 * D + D);
    o[t] = rv[t];
}

// ---------------- fallback full output assembly (carve path) ----------------
__global__ __launch_bounds__(256) void out_full_kernel(
    const float* __restrict__ x, const float* __restrict__ g,
    const float* __restrict__ regvec, const int* __restrict__ reg_indx,
    float* __restrict__ out)
{
    const int row = blockIdx.x * 2 + (threadIdx.x >> 7);
    const int t = threadIdx.x & 127;
    const int b = row >> 12;
    const int r = reg_indx[row];
    const float4* xr = (const float4*)(x + (size_t)row * D);
    const float4* rv = (const float4*)(regvec + ((size_t)b * R + r) * D);
    const float4* gr = (const float4*)(g + (size_t)b * D);
    float4* o = (float4*)(out + (size_t)row * 3 * D);
    o[t]       = xr[t];
    o[128 + t] = rv[t];
    o[256 + t] = gr[t];
}

extern "C" void kernel_launch(void* const* d_in, const int* in_sizes, int n_in,
                              void* d_out, int out_size, void* d_ws, size_t ws_size,
                              hipStream_t stream)
{
    (void)in_sizes; (void)n_in; (void)out_size;
    const float* x     = (const float*)d_in[0];
    const float* g_vec = (const float*)d_in[1];
    const float* occ_w = (const float*)d_in[2];
    const float* occ_b = (const float*)d_in[3];
    const float* w1    = (const float*)d_in[4];
    const float* b1    = (const float*)d_in[5];
    const float* w2    = (const float*)d_in[6];
    const float* b2    = (const float*)d_in[7];
    float* out = (float*)d_out;

    char* ws = (char*)d_ws;
    size_t off = 0;
    auto alloc = [&](size_t bytes) {
        char* p = ws + off; off = (off + bytes + 255) & ~(size_t)255; return p;
    };
    int*    reg_indx  = (int*)alloc((size_t)M * 4);
    float*  reg_logit = (float*)alloc((size_t)M * 4);
    int*    pcnt      = (int*)alloc(64 * R * 4);
    double* psum      = (double*)alloc(64 * R * 8);
    int*    counts    = (int*)alloc(B * R * 4);
    float*  regvec    = (float*)alloc((size_t)B * R * D * 4);

    const size_t xbB = (size_t)M * D * 2, wB = (size_t)D * D * 2;
    ushort *xb, *h1, *w1t, *w2t;
    int fused;                        // 1: ws holds intermediates, occ writes out.x/g
    if (ws_size >= off + 2 * xbB + 2 * wB + 1024) {
        fused = 1;
        xb  = (ushort*)alloc(xbB);
        h1  = (ushort*)alloc(xbB);
        w1t = (ushort*)alloc(wB);
        w2t = (ushort*)alloc(wB);
    } else {                          // carve from d_out; fully rewritten later
        fused = 0;
        char* o = (char*)d_out;
        xb  = (ushort*)o;
        h1  = (ushort*)(o + xbB);
        w1t = (ushort*)(o + 2 * xbB);
        w2t = (ushort*)(o + 2 * xbB + wB);
    }

    hipLaunchKernelGGL(occ_kernel, dim3(M / 32), dim3(256), 0, stream,
                       x, occ_w, occ_b, g_vec, reg_indx, reg_logit, xb, out, fused);
    hipLaunchKernelGGL(wtrans_kernel, dim3(512), dim3(256), 0, stream,
                       w1, w2, w1t, w2t);
    hipLaunchKernelGGL(loss_part_kernel, dim3(64), dim3(256), 0, stream,
                       reg_indx, reg_logit, pcnt, psum);
    hipLaunchKernelGGL(loss_final_kernel, dim3(1), dim3(128), 0, stream,
                       pcnt, psum, counts, out + OUT_ELEMS);
    hipLaunchKernelGGL(init_regvec_c2_kernel, dim3(16), dim3(256), 0, stream,
                       b1, w2, b2, counts, regvec);
    hipLaunchKernelGGL(gemm_mfma1, dim3((M / 128) * (D / 128)), dim3(256), 0, stream,
                       xb, w1t, b1, h1);
    hipLaunchKernelGGL(gemm_mfma2, dim3((M / 128) * (D / 128)), dim3(256), 0, stream,
                       h1, w2t, b2, reg_indx, regvec);
    if (fused) {
        hipLaunchKernelGGL(out_mid_kernel, dim3(M / 2), dim3(256), 0, stream,
                           regvec, reg_indx, out);
    } else {
        hipLaunchKernelGGL(out_full_kernel, dim3(M / 2), dim3(256), 0, stream,
                           x, g_vec, regvec, reg_indx, out);
    }
}

// Round 13
// 198.924 us; speedup vs baseline: 1.5337x; 1.5337x over previous
//
#include <hip/hip_runtime.h>
#include <cstdint>
#include <cstddef>

constexpr int B = 8, S = 4096, D = 512, R = 16;
constexpr int M = B * S;                         // 32768 rows
constexpr long long OUT_ELEMS = (long long)M * 3 * D;  // 50331648

typedef short short8 __attribute__((ext_vector_type(8)));
typedef float f32x4 __attribute__((ext_vector_type(4)));

__device__ __forceinline__ ushort f2bf(float f) {
    union { float f; unsigned u; } v; v.f = f;
    return (ushort)((v.u + 0x7fffu + ((v.u >> 16) & 1u)) >> 16);
}

__device__ __forceinline__ void gload_lds16(const void* g, void* l) {
    __builtin_amdgcn_global_load_lds(
        (const __attribute__((address_space(1))) void*)g,
        (__attribute__((address_space(3))) void*)l, 16, 0, 0);
}

// ---------------- prep: w1/w2 transpose+bf16 (blocks 0..511) ----------------
//                 + occ_w lane-major repack   (block 512)  [r11-proven]
// wP[(dg*32+k)*16 + r] = float4{occ_w[(d+j)*16+r], j=0..3}, d = dg*128+k*4.
// Phase-2 lane (dg,r) at iter k reads wP[(dg*32+k)*16+r]: the 16 lanes of a
// dg-group hit 256 CONTIGUOUS bytes (4 lines/instr vs 64 for row-major wT).
__global__ __launch_bounds__(256) void prep_kernel(
    const float* __restrict__ w1, const float* __restrict__ w2,
    ushort* __restrict__ w1t, ushort* __restrict__ w2t,
    const float* __restrict__ occ_w, float4* __restrict__ wP)
{
    const int tid = threadIdx.x;
    if (blockIdx.x == 512) {                      // ---- occ_w repack ----
        for (int i = tid; i < 2048; i += 256) {
            const int dgk = i >> 4;               // dg*32 + k
            const int r = i & 15;
            const int d = (dgk >> 5) * 128 + (dgk & 31) * 4;
            float4 v;
            v.x = occ_w[(size_t)(d + 0) * 16 + r];
            v.y = occ_w[(size_t)(d + 1) * 16 + r];
            v.z = occ_w[(size_t)(d + 2) * 16 + r];
            v.w = occ_w[(size_t)(d + 3) * 16 + r];
            wP[i] = v;
        }
        return;
    }
    __shared__ float tile[32][33];
    const int wb = blockIdx.x;                    // 0..511
    const float* w = (wb >> 8) ? w2 : w1;
    ushort* wt = (wb >> 8) ? w2t : w1t;
    const int rest = wb & 255;
    const int n0 = (rest & 15) * 32, k0 = (rest >> 4) * 32;
    const int tx = tid & 31, ty = tid >> 5;
#pragma unroll
    for (int qq = 0; qq < 4; ++qq)
        tile[ty * 4 + qq][tx] = w[(size_t)(k0 + ty * 4 + qq) * D + n0 + tx];
    __syncthreads();
#pragma unroll
    for (int qq = 0; qq < 4; ++qq)
        wt[(size_t)(n0 + ty * 4 + qq) * D + k0 + tx] = f2bf(tile[tx][ty * 4 + qq]);
}

// ---------------- occ logits + fused streaming copy (r8 base + wP access) ---
// 8192 blocks x 4 waves x 1 row.  Phase 1: per-lane coalesced copy of the
// row -> out.x, out.g, xb (no barriers -> stores retire under TLP).
// Phase 2: lane (dg=lane>>4, r=lane&15) accumulates logit r over d in
// [dg*128, dg*128+128): 32 x float4 (L1-hot after phase 1) + 32 wP float4
// (lane-major layout, 4 lines/instr).  Per-row VMEM: 73 instrs (r8: 169).
// Values & per-lane summation order BIT-IDENTICAL to r7/r8/r11.
__global__ __launch_bounds__(256) void occ_kernel(
    const float* __restrict__ x, const float4* __restrict__ wP,
    const float* __restrict__ occ_b, const float* __restrict__ g_vec,
    int* __restrict__ reg_indx, float* __restrict__ reg_logit,
    ushort* __restrict__ xb, float* __restrict__ out, int writeOut)
{
    const int wave = threadIdx.x >> 6, lane = threadIdx.x & 63;
    const int dg = lane >> 4, r = lane & 15;
    const int row = blockIdx.x * 4 + wave;
    const double bias = (double)occ_b[r];
    const float4* xrow4 = (const float4*)(x + (size_t)row * D);
    // ---- phase 1: coalesced copy ----
    const float4 c0 = xrow4[lane * 2], c1 = xrow4[lane * 2 + 1];
    short8 pk;
    pk[0] = (short)f2bf(c0.x); pk[1] = (short)f2bf(c0.y);
    pk[2] = (short)f2bf(c0.z); pk[3] = (short)f2bf(c0.w);
    pk[4] = (short)f2bf(c1.x); pk[5] = (short)f2bf(c1.y);
    pk[6] = (short)f2bf(c1.z); pk[7] = (short)f2bf(c1.w);
    *(short8*)&xb[(size_t)row * D + lane * 8] = pk;
    if (writeOut) {
        float* orow = out + (size_t)row * 3 * D;
        ((float4*)orow)[lane * 2]     = c0;
        ((float4*)orow)[lane * 2 + 1] = c1;
        const float4* gr4 = (const float4*)(g_vec + (size_t)(row >> 12) * D);
        ((float4*)(orow + 2 * D))[lane * 2]     = gr4[lane * 2];
        ((float4*)(orow + 2 * D))[lane * 2 + 1] = gr4[lane * 2 + 1];
    }
    // ---- phase 2: fp64 dot (order identical to r7/r8; wP values = ww0..3) --
    const float4* xr4 = xrow4 + dg * 32;
    const float4* wp4 = wP + (size_t)(dg * 32) * 16 + r;
    double a0 = 0.0, a1 = 0.0, a2 = 0.0, a3 = 0.0;
#pragma unroll 4
    for (int k = 0; k < 32; ++k) {
        const float4 xv = xr4[k];
        const float4 wv = wp4[k * 16];
        a0 += (double)xv.x * (double)wv.x;
        a1 += (double)xv.y * (double)wv.y;
        a2 += (double)xv.z * (double)wv.z;
        a3 += (double)xv.w * (double)wv.w;
    }
    double s = (a0 + a1) + (a2 + a3);
    s += __shfl_xor(s, 16, 64);
    s += __shfl_xor(s, 32, 64);
    s += bias;                                    // lane's logit, r = lane&15
    double mv = s; int mi = r;
#pragma unroll
    for (int off = 1; off < 16; off <<= 1) {
        const double ov = __shfl_xor(mv, off, 64);
        const int    oi = __shfl_xor(mi, off, 64);
        if (ov > mv || (ov == mv && oi < mi)) { mv = ov; mi = oi; }
    }
    float ef = expf((float)(s - mv));
#pragma unroll
    for (int off = 1; off < 16; off <<= 1) ef += __shfl_xor(ef, off, 64);
    if (lane == 0) { reg_indx[row] = mi; reg_logit[row] = 1.0f / ef; }
}

// ---------------- loss partials: 64 blocks = (batch, chunk-of-512-rows) ----
__global__ __launch_bounds__(256) void loss_part_kernel(
    const int* __restrict__ reg_indx, const float* __restrict__ reg_logit,
    int* __restrict__ pcnt, double* __restrict__ psum)
{
    const int b = blockIdx.x >> 3, c = blockIdx.x & 7;
    const int t = threadIdx.x;
    __shared__ double ssum[R][257];
    __shared__ int    scnt[R][257];
#pragma unroll
    for (int r = 0; r < R; ++r) { ssum[r][t] = 0.0; scnt[r][t] = 0; }
    __syncthreads();
    const int base = b * S + c * 512;
    for (int s = t; s < 512; s += 256) {
        const int r = reg_indx[base + s];
        ssum[r][t] += (double)reg_logit[base + s];
        scnt[r][t] += 1;
    }
    __syncthreads();
    for (int off = 128; off > 0; off >>= 1) {
        if (t < off) {
#pragma unroll
            for (int r = 0; r < R; ++r) {
                ssum[r][t] += ssum[r][t + off];
                scnt[r][t] += scnt[r][t + off];
            }
        }
        __syncthreads();
    }
    if (t < R) {
        psum[blockIdx.x * R + t] = ssum[t][0];
        pcnt[blockIdx.x * R + t] = scnt[t][0];
    }
}

// ---------------- loss final: combine partials, emit counts + scalar loss ---
__global__ void loss_final_kernel(const int* __restrict__ pcnt,
                                  const double* __restrict__ psum,
                                  int* __restrict__ counts,
                                  float* __restrict__ out_loss)
{
    __shared__ double m2[128];
    const int t = threadIdx.x;            // 128 threads = (b,r)
    const int b = t >> 4, r = t & 15;
    int cnt = 0; double s = 0.0;
#pragma unroll
    for (int c = 0; c < 8; ++c) {
        cnt += pcnt[(b * 8 + c) * R + r];
        s   += psum[(b * 8 + c) * R + r];
    }
    counts[b * R + r] = cnt;
    const double mean = s / (double)S;
    m2[t] = mean * mean;
    __syncthreads();
    if (t == 0) {
        double tot = 0.0;
        for (int i = 0; i < 128; ++i) tot += m2[i];
        *out_loss = (float)(tot / (double)B);
    }
}

// ---------------- fused c2 compute + regvec init, 16 blocks ------------------
__global__ __launch_bounds__(256) void init_regvec_c2_kernel(
    const float* __restrict__ b1, const float* __restrict__ w2,
    const float* __restrict__ b2, const int* __restrict__ counts,
    float* __restrict__ regvec)
{
    __shared__ float c1[D];
    __shared__ float part[8][33];
    const int t = threadIdx.x;
    c1[t]       = fmaxf(b1[t], 0.f);
    c1[t + 256] = fmaxf(b1[t + 256], 0.f);
    __syncthreads();
    const int dl = t & 31, kg = t >> 5;        // 8 k-groups x 64 k
    const int d = blockIdx.x * 32 + dl;
    float p = 0.f;
    for (int k = kg * 64; k < kg * 64 + 64; ++k)
        p += c1[k] * w2[(size_t)k * D + d];
    part[kg][dl] = p;
    __syncthreads();
    if (t < 32) {
        const int dd = blockIdx.x * 32 + t;
        float acc = b2[dd];
#pragma unroll
        for (int kk = 0; kk < 8; ++kk) acc += part[kk][t];
        const float c2d = fmaxf(acc, 0.f);
        for (int br = 0; br < B * R; ++br)
            regvec[(size_t)br * D + dd] = (counts[br] < S) ? c2d : 0.f;
    }
}

// ================= MFMA GEMM: 128x128 tile, 4 waves, 16x16x32 bf16 ==========
struct GemmCtx {
    int row0, col0, wave, lane, wr, wc;
    unsigned dsto[2];
    const ushort *aSrc[2], *bSrc[2];
    unsigned aOff[4], bOff[4];
};

__device__ __forceinline__ void gemm_setup(
    GemmCtx& c, const ushort* Ab, const ushort* Bt)
{
    const int tid = threadIdx.x;
    c.wave = tid >> 6; c.lane = tid & 63;
    c.wr = c.wave >> 1; c.wc = c.wave & 1;
    // bijective XCD swizzle over nwg=1024 (8 XCDs x 128 chunks)
    const int orig = blockIdx.x;
    const int wg = (orig & 7) * 128 + (orig >> 3);
    c.row0 = (wg >> 2) * 128;   // 256 mtiles
    c.col0 = (wg & 3) * 128;    // 4 ntiles
#pragma unroll
    for (int q = 0; q < 2; ++q) {
        const unsigned o = (unsigned)(c.wave * 2 + q) * 1024u + (unsigned)c.lane * 16u;
        c.dsto[q] = (unsigned)(c.wave * 2 + q) * 1024u;
        const unsigned r  = ((o >> 7) << 1) | (((o >> 6) ^ (o >> 8)) & 1u);
        const unsigned kg = ((o >> 4) & 3u) ^ (r & 3u);
        c.aSrc[q] = Ab + (size_t)(c.row0 + r) * D + kg * 8;
        c.bSrc[q] = Bt + (size_t)(c.col0 + r) * D + kg * 8;
    }
#pragma unroll
    for (int i = 0; i < 4; ++i) {
        const unsigned kg = (unsigned)(c.lane >> 4);
        unsigned r = (unsigned)(c.wr * 64 + i * 16 + (c.lane & 15));
        c.aOff[i] = ((r << 6) + (kg << 4)) ^ ((r & 7u) << 4);
        r = (unsigned)(c.wc * 64 + i * 16 + (c.lane & 15));
        c.bOff[i] = ((r << 6) + (kg << 4)) ^ ((r & 7u) << 4);
    }
}

#define STAGE4(ctx, smA, smB, bufofs, kt)                                 \
    gload_lds16(ctx.aSrc[0] + (kt), smA + (bufofs) + ctx.dsto[0]);        \
    gload_lds16(ctx.aSrc[1] + (kt), smA + (bufofs) + ctx.dsto[1]);        \
    gload_lds16(ctx.bSrc[0] + (kt), smB + (bufofs) + ctx.dsto[0]);        \
    gload_lds16(ctx.bSrc[1] + (kt), smB + (bufofs) + ctx.dsto[1]);

#define GEMM_KLOOP(smA, smB, ctx, acc)                                         \
    STAGE4(ctx, smA, smB, 0, 0)                                                \
    __syncthreads();                                                           \
    _Pragma("unroll")                                                          \
    for (int t = 0; t < 16; ++t) {                                             \
        const int co = (t & 1) * 8192;                                         \
        if (t < 15) { STAGE4(ctx, smA, smB, co ^ 8192, (t + 1) * 32) }         \
        short8 a[4], b[4];                                                     \
        _Pragma("unroll")                                                      \
        for (int i = 0; i < 4; ++i)                                            \
            a[i] = *(const short8*)(smA + co + ctx.aOff[i]);                   \
        _Pragma("unroll")                                                      \
        for (int j = 0; j < 4; ++j)                                            \
            b[j] = *(const short8*)(smB + co + ctx.bOff[j]);                   \
        _Pragma("unroll")                                                      \
        for (int i = 0; i < 4; ++i)                                            \
            _Pragma("unroll")                                                  \
            for (int j = 0; j < 4; ++j)                                        \
                acc[i][j] = __builtin_amdgcn_mfma_f32_16x16x32_bf16(           \
                    a[i], b[j], acc[i][j], 0, 0, 0);                           \
        __syncthreads();                                                       \
    }

// GEMM1: h1 = relu(xb @ w1t^T + b1), bf16 out
__global__ __launch_bounds__(256, 2) void gemm_mfma1(
    const ushort* __restrict__ Ab, const ushort* __restrict__ Bt,
    const float* __restrict__ bias, ushort* __restrict__ H)
{
    __shared__ ushort As[8192];
    __shared__ ushort Bs[8192];
    GemmCtx c; gemm_setup(c, Ab, Bt);
    char* smA = (char*)As; char* smB = (char*)Bs;
    f32x4 acc[4][4];
#pragma unroll
    for (int i = 0; i < 4; ++i)
#pragma unroll
        for (int j = 0; j < 4; ++j) acc[i][j] = (f32x4)0.f;
    GEMM_KLOOP(smA, smB, c, acc)
    float bb[4];
#pragma unroll
    for (int j = 0; j < 4; ++j) bb[j] = bias[c.col0 + c.wc * 64 + j * 16 + (c.lane & 15)];
#pragma unroll
    for (int i = 0; i < 4; ++i) {
        const int row = c.row0 + c.wr * 64 + i * 16 + ((c.lane >> 4) << 2);
#pragma unroll
        for (int j = 0; j < 4; ++j) {
            const int col = c.col0 + c.wc * 64 + j * 16 + (c.lane & 15);
#pragma unroll
            for (int ii = 0; ii < 4; ++ii) {
                const float v = fmaxf(acc[i][j][ii] + bb[j], 0.f);
                H[(size_t)(row + ii) * D + col] = f2bf(v);
            }
        }
    }
}

// GEMM2: v = relu(h1 @ w2t^T + b2); segmented max by reg_indx into regvec
__global__ __launch_bounds__(256, 2) void gemm_mfma2(
    const ushort* __restrict__ Ab, const ushort* __restrict__ Bt,
    const float* __restrict__ bias, const int* __restrict__ reg_indx,
    float* __restrict__ regvec)
{
    __shared__ ushort As[8192];
    __shared__ ushort Bs[8192];
    __shared__ unsigned redmax[R * 128];
    __shared__ int rowreg[128];
    GemmCtx c; gemm_setup(c, Ab, Bt);
    char* smA = (char*)As; char* smB = (char*)Bs;
    const int tid = threadIdx.x;
    if (tid < 128) rowreg[tid] = reg_indx[c.row0 + tid];
#pragma unroll
    for (int q = 0; q < 8; ++q) redmax[tid + q * 256] = 0u;
    f32x4 acc[4][4];
#pragma unroll
    for (int i = 0; i < 4; ++i)
#pragma unroll
        for (int j = 0; j < 4; ++j) acc[i][j] = (f32x4)0.f;
    GEMM_KLOOP(smA, smB, c, acc)   // barriers inside make the init visible
    float bb[4];
#pragma unroll
    for (int j = 0; j < 4; ++j) bb[j] = bias[c.col0 + c.wc * 64 + j * 16 + (c.lane & 15)];
#pragma unroll
    for (int i = 0; i < 4; ++i) {
        const int lrow = c.wr * 64 + i * 16 + ((c.lane >> 4) << 2);
#pragma unroll
        for (int j = 0; j < 4; ++j) {
            const int lcol = c.wc * 64 + j * 16 + (c.lane & 15);
#pragma unroll
            for (int ii = 0; ii < 4; ++ii) {
                const float v = fmaxf(acc[i][j][ii] + bb[j], 0.f);
                atomicMax(&redmax[rowreg[lrow + ii] * 128 + lcol], __float_as_uint(v));
            }
        }
    }
    __syncthreads();
    const int b = c.row0 >> 12;
#pragma unroll
    for (int q = 0; q < 8; ++q) {
        const int idx = tid + q * 256;
        const int r = idx >> 7, col = idx & 127;
        atomicMax((unsigned*)&regvec[(((size_t)b * R + r) << 9) + c.col0 + col],
                  redmax[idx]);
    }
}

// ---------------- output: middle slice only (x/g written by occ) ------------
__global__ __launch_bounds__(256) void out_mid_kernel(
    const float* __restrict__ regvec, const int* __restrict__ reg_indx,
    float* __restrict__ out)
{
    const int row = blockIdx.x * 2 + (threadIdx.x >> 7);
    const int t = threadIdx.x & 127;
    const int b = row >> 12;
    const int r = reg_indx[row];
    const float4* rv = (const float4*)(regvec + ((size_t)b * R + r) * D);
    float4* o = (float4*)(out + (size_t)row * 3 * D + D);
    o[t] = rv[t];
}

// ---------------- fallback full output assembly (carve path) ----------------
__global__ __launch_bounds__(256) void out_full_kernel(
    const float* __restrict__ x, const float* __restrict__ g,
    const float* __restrict__ regvec, const int* __restrict__ reg_indx,
    float* __restrict__ out)
{
    const int row = blockIdx.x * 2 + (threadIdx.x >> 7);
    const int t = threadIdx.x & 127;
    const int b = row >> 12;
    const int r = reg_indx[row];
    const float4* xr = (const float4*)(x + (size_t)row * D);
    const float4* rv = (const float4*)(regvec + ((size_t)b * R + r) * D);
    const float4* gr = (const float4*)(g + (size_t)b * D);
    float4* o = (float4*)(out + (size_t)row * 3 * D);
    o[t]       = xr[t];
    o[128 + t] = rv[t];
    o[256 + t] = gr[t];
}

extern "C" void kernel_launch(void* const* d_in, const int* in_sizes, int n_in,
                              void* d_out, int out_size, void* d_ws, size_t ws_size,
                              hipStream_t stream)
{
    (void)in_sizes; (void)n_in; (void)out_size;
    const float* x     = (const float*)d_in[0];
    const float* g_vec = (const float*)d_in[1];
    const float* occ_w = (const float*)d_in[2];
    const float* occ_b = (const float*)d_in[3];
    const float* w1    = (const float*)d_in[4];
    const float* b1    = (const float*)d_in[5];
    const float* w2    = (const float*)d_in[6];
    const float* b2    = (const float*)d_in[7];
    float* out = (float*)d_out;

    char* ws = (char*)d_ws;
    size_t off = 0;
    auto alloc = [&](size_t bytes) {
        char* p = ws + off; off = (off + bytes + 255) & ~(size_t)255; return p;
    };
    int*    reg_indx  = (int*)alloc((size_t)M * 4);
    float*  reg_logit = (float*)alloc((size_t)M * 4);
    int*    pcnt      = (int*)alloc(64 * R * 4);
    double* psum      = (double*)alloc(64 * R * 8);
    int*    counts    = (int*)alloc(B * R * 4);
    float*  regvec    = (float*)alloc((size_t)B * R * D * 4);
    float4* wP        = (float4*)alloc((size_t)D * R * 4);

    const size_t xbB = (size_t)M * D * 2, wB = (size_t)D * D * 2;
    ushort *xb, *h1, *w1t, *w2t;
    int fused;                        // 1: ws holds intermediates, occ writes out.x/g
    if (ws_size >= off + 2 * xbB + 2 * wB + 1024) {
        fused = 1;
        xb  = (ushort*)alloc(xbB);
        h1  = (ushort*)alloc(xbB);
        w1t = (ushort*)alloc(wB);
        w2t = (ushort*)alloc(wB);
    } else {                          // carve from d_out; fully rewritten later
        fused = 0;
        char* o = (char*)d_out;
        xb  = (ushort*)o;
        h1  = (ushort*)(o + xbB);
        w1t = (ushort*)(o + 2 * xbB);
        w2t = (ushort*)(o + 2 * xbB + wB);
    }

    hipLaunchKernelGGL(prep_kernel, dim3(513), dim3(256), 0, stream,
                       w1, w2, w1t, w2t, occ_w, wP);
    hipLaunchKernelGGL(occ_kernel, dim3(M / 4), dim3(256), 0, stream,
                       x, wP, occ_b, g_vec, reg_indx, reg_logit, xb, out, fused);
    hipLaunchKernelGGL(loss_part_kernel, dim3(64), dim3(256), 0, stream,
                       reg_indx, reg_logit, pcnt, psum);
    hipLaunchKernelGGL(loss_final_kernel, dim3(1), dim3(128), 0, stream,
                       pcnt, psum, counts, out + OUT_ELEMS);
    hipLaunchKernelGGL(init_regvec_c2_kernel, dim3(16), dim3(256), 0, stream,
                       b1, w2, b2, counts, regvec);
    hipLaunchKernelGGL(gemm_mfma1, dim3((M / 128) * (D / 128)), dim3(256), 0, stream,
                       xb, w1t, b1, h1);
    hipLaunchKernelGGL(gemm_mfma2, dim3((M / 128) * (D / 128)), dim3(256), 0, stream,
                       h1, w2t, b2, reg_indx, regvec);
    if (fused) {
        hipLaunchKernelGGL(out_mid_kernel, dim3(M / 2), dim3(256), 0, stream,
                           regvec, reg_indx, out);
    } else {
        hipLaunchKernelGGL(out_full_kernel, dim3(M / 2), dim3(256), 0, stream,
                           x, g_vec, regvec, reg_indx, out);
    }
}

// Round 14
// 152.601 us; speedup vs baseline: 1.9993x; 1.3036x over previous
//
#include <hip/hip_runtime.h>
#include <cstdint>
#include <cstddef>

constexpr int B = 8, S = 4096, D = 512, R = 16;
constexpr int M = B * S;                         // 32768 rows
constexpr long long OUT_ELEMS = (long long)M * 3 * D;  // 50331648

typedef short short8 __attribute__((ext_vector_type(8)));
typedef short short4v __attribute__((ext_vector_type(4)));
typedef float f32x4 __attribute__((ext_vector_type(4)));

__device__ __forceinline__ ushort f2bf(float f) {
    union { float f; unsigned u; } v; v.f = f;
    return (ushort)((v.u + 0x7fffu + ((v.u >> 16) & 1u)) >> 16);
}

__device__ __forceinline__ void gload_lds16(const void* g, void* l) {
    __builtin_amdgcn_global_load_lds(
        (const __attribute__((address_space(1))) void*)g,
        (__attribute__((address_space(3))) void*)l, 16, 0, 0);
}

// ---------------- occ: LDS-shared GEMM-style logits + fused copy ------------
// 512 blocks x 4 waves x 16 rows.  wT[logit][k] staged once (ONE barrier,
// before any global stores).  Each wave owns a PRIVATE x-chunk LDS buffer
// (no cross-wave sync -> no barriers in the loop -> no store drains).
// Per chunk of 64 k: wave stages x[16 rows][64] (4 float4/lane, coalesced),
// the SAME registers feed out.x + xb stores; ds_write -> wave-local
// lgkmcnt(0); lane (rowgrp=lane>>4, logit=lane&15) accumulates 4 rows'
// logit over the chunk: x reads 16-lane broadcast (free), w reads 16
// distinct consecutive (2-way, free).  Per-lane VMEM data: ~4KB per 16-row
// set vs 64KB/row before.  Epilogue: 16-lane argmax butterfly (same
// compare + first-occurrence tie rule as all passing rounds) + expf sum.
__global__ __launch_bounds__(256) void occ_kernel(
    const float* __restrict__ x, const float* __restrict__ occ_w,
    const float* __restrict__ occ_b, const float* __restrict__ g_vec,
    int* __restrict__ reg_indx, float* __restrict__ reg_logit,
    ushort* __restrict__ xb, float* __restrict__ out, int writeOut)
{
    __shared__ float wT[16][516];      // wT[logit][k], rows 16B-aligned, 33KB
    __shared__ float xs[4][16][68];    // per-wave [16 rows][64 k], 17.4KB
    const int tid = threadIdx.x;
    for (int idx = tid; idx < D * R; idx += 256)   // wT[r][k] = occ_w[k*16+r]
        wT[idx & 15][idx >> 4] = occ_w[idx];
    __syncthreads();                   // ONLY barrier; no global stores yet
    const int wave = tid >> 6, lane = tid & 63;
    const int logit = lane & 15, rowgrp = lane >> 4;
    const int row0 = blockIdx.x * 64 + wave * 16;  // wave's 16 rows
    const int bat = row0 >> 12;
    float (*xw)[68] = xs[wave];
    const float* xbase = x + (size_t)row0 * D;
    const int kq4 = (lane & 15) * 4;               // staging col for this lane
    double acc[4] = {0.0, 0.0, 0.0, 0.0};
    float4 st[4];
#pragma unroll
    for (int i = 0; i < 4; ++i)        // prologue: chunk 0 (rows i*4+rowgrp)
        st[i] = *(const float4*)&xbase[(size_t)(i * 4 + rowgrp) * D + kq4];
#pragma unroll 1
    for (int c = 0; c < 8; ++c) {
        const int k0 = c * 64;
        float4 nx[4];
        if (c < 7) {
#pragma unroll
            for (int i = 0; i < 4; ++i)
                nx[i] = *(const float4*)&xbase[(size_t)(i * 4 + rowgrp) * D + k0 + 64 + kq4];
        }
        // copy-out + LDS write of current chunk (from held registers)
        asm volatile("s_waitcnt lgkmcnt(0)" ::: "memory");  // reads of c-1 done
#pragma unroll
        for (int i = 0; i < 4; ++i) {
            const int rl = i * 4 + rowgrp;
            const int row = row0 + rl;
            short4v pk;
            pk[0] = (short)f2bf(st[i].x); pk[1] = (short)f2bf(st[i].y);
            pk[2] = (short)f2bf(st[i].z); pk[3] = (short)f2bf(st[i].w);
            *(short4v*)&xb[(size_t)row * D + k0 + kq4] = pk;
            if (writeOut)
                *(float4*)&out[(size_t)row * 3 * D + k0 + kq4] = st[i];
            *(float4*)&xw[rl][kq4] = st[i];
        }
        asm volatile("s_waitcnt lgkmcnt(0)" ::: "memory");  // writes visible
        // compute: 16 k-quads; x broadcast across 16 lanes, w 2-way banks
#pragma unroll 4
        for (int k = 0; k < 64; k += 4) {
            const f32x4 wv = *(const f32x4*)&wT[logit][k0 + k];
#pragma unroll
            for (int j = 0; j < 4; ++j) {
                const f32x4 xv = *(const f32x4*)&xw[rowgrp * 4 + j][k];
                acc[j] += (double)xv[0] * (double)wv[0];
                acc[j] += (double)xv[1] * (double)wv[1];
                acc[j] += (double)xv[2] * (double)wv[2];
                acc[j] += (double)xv[3] * (double)wv[3];
            }
        }
#pragma unroll
        for (int i = 0; i < 4; ++i) st[i] = nx[i];
    }
    // ---- epilogue: per-row argmax within each 16-lane group ----
    const double bias = (double)occ_b[logit];
#pragma unroll
    for (int j = 0; j < 4; ++j) {
        const double s = acc[j] + bias;            // lane's logit for its row
        double mv = s; int mi = logit;
#pragma unroll
        for (int off = 1; off < 16; off <<= 1) {
            const double ov = __shfl_xor(mv, off, 64);
            const int    oi = __shfl_xor(mi, off, 64);
            if (ov > mv || (ov == mv && oi < mi)) { mv = ov; mi = oi; }
        }
        float ef = expf((float)(s - mv));
#pragma unroll
        for (int off = 1; off < 16; off <<= 1) ef += __shfl_xor(ef, off, 64);
        if (logit == 0) {
            const int row = row0 + rowgrp * 4 + j;
            reg_indx[row] = mi; reg_logit[row] = 1.0f / ef;
        }
    }
    // ---- g broadcast copy (no barriers follow; stores retire via TLP) ----
    if (writeOut) {
        const float4* gr4 = (const float4*)(g_vec + (size_t)bat * D);
        const float4 g0 = gr4[lane * 2], g1 = gr4[lane * 2 + 1];
#pragma unroll 1
        for (int rl = 0; rl < 16; ++rl) {
            float* orow = out + (size_t)(row0 + rl) * 3 * D + 2 * D;
            ((float4*)orow)[lane * 2]     = g0;
            ((float4*)orow)[lane * 2 + 1] = g1;
        }
    }
}

// ---------------- wtrans: w1/w2 transpose + bf16 convert --------------------
__global__ __launch_bounds__(256) void wtrans_kernel(
    const float* __restrict__ w1, const float* __restrict__ w2,
    ushort* __restrict__ w1t, ushort* __restrict__ w2t)
{
    __shared__ float tile[32][33];
    const int tid = threadIdx.x;
    const int wb = blockIdx.x;                    // 0..511
    const float* w = (wb >> 8) ? w2 : w1;
    ushort* wt = (wb >> 8) ? w2t : w1t;
    const int rest = wb & 255;
    const int n0 = (rest & 15) * 32, k0 = (rest >> 4) * 32;
    const int tx = tid & 31, ty = tid >> 5;
#pragma unroll
    for (int qq = 0; qq < 4; ++qq)
        tile[ty * 4 + qq][tx] = w[(size_t)(k0 + ty * 4 + qq) * D + n0 + tx];
    __syncthreads();
#pragma unroll
    for (int qq = 0; qq < 4; ++qq)
        wt[(size_t)(n0 + ty * 4 + qq) * D + k0 + tx] = f2bf(tile[tx][ty * 4 + qq]);
}

// ---------------- loss partials: 64 blocks = (batch, chunk-of-512-rows) ----
__global__ __launch_bounds__(256) void loss_part_kernel(
    const int* __restrict__ reg_indx, const float* __restrict__ reg_logit,
    int* __restrict__ pcnt, double* __restrict__ psum)
{
    const int b = blockIdx.x >> 3, c = blockIdx.x & 7;
    const int t = threadIdx.x;
    __shared__ double ssum[R][257];
    __shared__ int    scnt[R][257];
#pragma unroll
    for (int r = 0; r < R; ++r) { ssum[r][t] = 0.0; scnt[r][t] = 0; }
    __syncthreads();
    const int base = b * S + c * 512;
    for (int s = t; s < 512; s += 256) {
        const int r = reg_indx[base + s];
        ssum[r][t] += (double)reg_logit[base + s];
        scnt[r][t] += 1;
    }
    __syncthreads();
    for (int off = 128; off > 0; off >>= 1) {
        if (t < off) {
#pragma unroll
            for (int r = 0; r < R; ++r) {
                ssum[r][t] += ssum[r][t + off];
                scnt[r][t] += scnt[r][t + off];
            }
        }
        __syncthreads();
    }
    if (t < R) {
        psum[blockIdx.x * R + t] = ssum[t][0];
        pcnt[blockIdx.x * R + t] = scnt[t][0];
    }
}

// ---------------- loss final: combine partials, emit counts + scalar loss ---
__global__ void loss_final_kernel(const int* __restrict__ pcnt,
                                  const double* __restrict__ psum,
                                  int* __restrict__ counts,
                                  float* __restrict__ out_loss)
{
    __shared__ double m2[128];
    const int t = threadIdx.x;            // 128 threads = (b,r)
    const int b = t >> 4, r = t & 15;
    int cnt = 0; double s = 0.0;
#pragma unroll
    for (int c = 0; c < 8; ++c) {
        cnt += pcnt[(b * 8 + c) * R + r];
        s   += psum[(b * 8 + c) * R + r];
    }
    counts[b * R + r] = cnt;
    const double mean = s / (double)S;
    m2[t] = mean * mean;
    __syncthreads();
    if (t == 0) {
        double tot = 0.0;
        for (int i = 0; i < 128; ++i) tot += m2[i];
        *out_loss = (float)(tot / (double)B);
    }
}

// ---------------- fused c2 compute + regvec init, 16 blocks ------------------
__global__ __launch_bounds__(256) void init_regvec_c2_kernel(
    const float* __restrict__ b1, const float* __restrict__ w2,
    const float* __restrict__ b2, const int* __restrict__ counts,
    float* __restrict__ regvec)
{
    __shared__ float c1[D];
    __shared__ float part[8][33];
    const int t = threadIdx.x;
    c1[t]       = fmaxf(b1[t], 0.f);
    c1[t + 256] = fmaxf(b1[t + 256], 0.f);
    __syncthreads();
    const int dl = t & 31, kg = t >> 5;        // 8 k-groups x 64 k
    const int d = blockIdx.x * 32 + dl;
    float p = 0.f;
    for (int k = kg * 64; k < kg * 64 + 64; ++k)
        p += c1[k] * w2[(size_t)k * D + d];
    part[kg][dl] = p;
    __syncthreads();
    if (t < 32) {
        const int dd = blockIdx.x * 32 + t;
        float acc = b2[dd];
#pragma unroll
        for (int kk = 0; kk < 8; ++kk) acc += part[kk][t];
        const float c2d = fmaxf(acc, 0.f);
        for (int br = 0; br < B * R; ++br)
            regvec[(size_t)br * D + dd] = (counts[br] < S) ? c2d : 0.f;
    }
}

// ================= MFMA GEMM: 128x128 tile, 4 waves, 16x16x32 bf16 ==========
struct GemmCtx {
    int row0, col0, wave, lane, wr, wc;
    unsigned dsto[2];
    const ushort *aSrc[2], *bSrc[2];
    unsigned aOff[4], bOff[4];
};

__device__ __forceinline__ void gemm_setup(
    GemmCtx& c, const ushort* Ab, const ushort* Bt)
{
    const int tid = threadIdx.x;
    c.wave = tid >> 6; c.lane = tid & 63;
    c.wr = c.wave >> 1; c.wc = c.wave & 1;
    // bijective XCD swizzle over nwg=1024 (8 XCDs x 128 chunks)
    const int orig = blockIdx.x;
    const int wg = (orig & 7) * 128 + (orig >> 3);
    c.row0 = (wg >> 2) * 128;   // 256 mtiles
    c.col0 = (wg & 3) * 128;    // 4 ntiles
#pragma unroll
    for (int q = 0; q < 2; ++q) {
        const unsigned o = (unsigned)(c.wave * 2 + q) * 1024u + (unsigned)c.lane * 16u;
        c.dsto[q] = (unsigned)(c.wave * 2 + q) * 1024u;
        const unsigned r  = ((o >> 7) << 1) | (((o >> 6) ^ (o >> 8)) & 1u);
        const unsigned kg = ((o >> 4) & 3u) ^ (r & 3u);
        c.aSrc[q] = Ab + (size_t)(c.row0 + r) * D + kg * 8;
        c.bSrc[q] = Bt + (size_t)(c.col0 + r) * D + kg * 8;
    }
#pragma unroll
    for (int i = 0; i < 4; ++i) {
        const unsigned kg = (unsigned)(c.lane >> 4);
        unsigned r = (unsigned)(c.wr * 64 + i * 16 + (c.lane & 15));
        c.aOff[i] = ((r << 6) + (kg << 4)) ^ ((r & 7u) << 4);
        r = (unsigned)(c.wc * 64 + i * 16 + (c.lane & 15));
        c.bOff[i] = ((r << 6) + (kg << 4)) ^ ((r & 7u) << 4);
    }
}

#define STAGE4(ctx, smA, smB, bufofs, kt)                                 \
    gload_lds16(ctx.aSrc[0] + (kt), smA + (bufofs) + ctx.dsto[0]);        \
    gload_lds16(ctx.aSrc[1] + (kt), smA + (bufofs) + ctx.dsto[1]);        \
    gload_lds16(ctx.bSrc[0] + (kt), smB + (bufofs) + ctx.dsto[0]);        \
    gload_lds16(ctx.bSrc[1] + (kt), smB + (bufofs) + ctx.dsto[1]);

#define GEMM_KLOOP(smA, smB, ctx, acc)                                         \
    STAGE4(ctx, smA, smB, 0, 0)                                                \
    __syncthreads();                                                           \
    _Pragma("unroll")                                                          \
    for (int t = 0; t < 16; ++t) {                                             \
        const int co = (t & 1) * 8192;                                         \
        if (t < 15) { STAGE4(ctx, smA, smB, co ^ 8192, (t + 1) * 32) }         \
        short8 a[4], b[4];                                                     \
        _Pragma("unroll")                                                      \
        for (int i = 0; i < 4; ++i)                                            \
            a[i] = *(const short8*)(smA + co + ctx.aOff[i]);                   \
        _Pragma("unroll")                                                      \
        for (int j = 0; j < 4; ++j)                                            \
            b[j] = *(const short8*)(smB + co + ctx.bOff[j]);                   \
        _Pragma("unroll")                                                      \
        for (int i = 0; i < 4; ++i)                                            \
            _Pragma("unroll")                                                  \
            for (int j = 0; j < 4; ++j)                                        \
                acc[i][j] = __builtin_amdgcn_mfma_f32_16x16x32_bf16(           \
                    a[i], b[j], acc[i][j], 0, 0, 0);                           \
        __syncthreads();                                                       \
    }

// GEMM1: h1 = relu(xb @ w1t^T + b1), bf16 out
__global__ __launch_bounds__(256, 2) void gemm_mfma1(
    const ushort* __restrict__ Ab, const ushort* __restrict__ Bt,
    const float* __restrict__ bias, ushort* __restrict__ H)
{
    __shared__ ushort As[8192];
    __shared__ ushort Bs[8192];
    GemmCtx c; gemm_setup(c, Ab, Bt);
    char* smA = (char*)As; char* smB = (char*)Bs;
    f32x4 acc[4][4];
#pragma unroll
    for (int i = 0; i < 4; ++i)
#pragma unroll
        for (int j = 0; j < 4; ++j) acc[i][j] = (f32x4)0.f;
    GEMM_KLOOP(smA, smB, c, acc)
    float bb[4];
#pragma unroll
    for (int j = 0; j < 4; ++j) bb[j] = bias[c.col0 + c.wc * 64 + j * 16 + (c.lane & 15)];
#pragma unroll
    for (int i = 0; i < 4; ++i) {
        const int row = c.row0 + c.wr * 64 + i * 16 + ((c.lane >> 4) << 2);
#pragma unroll
        for (int j = 0; j < 4; ++j) {
            const int col = c.col0 + c.wc * 64 + j * 16 + (c.lane & 15);
#pragma unroll
            for (int ii = 0; ii < 4; ++ii) {
                const float v = fmaxf(acc[i][j][ii] + bb[j], 0.f);
                H[(size_t)(row + ii) * D + col] = f2bf(v);
            }
        }
    }
}

// GEMM2: v = relu(h1 @ w2t^T + b2); segmented max by reg_indx into regvec
__global__ __launch_bounds__(256, 2) void gemm_mfma2(
    const ushort* __restrict__ Ab, const ushort* __restrict__ Bt,
    const float* __restrict__ bias, const int* __restrict__ reg_indx,
    float* __restrict__ regvec)
{
    __shared__ ushort As[8192];
    __shared__ ushort Bs[8192];
    __shared__ unsigned redmax[R * 128];
    __shared__ int rowreg[128];
    GemmCtx c; gemm_setup(c, Ab, Bt);
    char* smA = (char*)As; char* smB = (char*)Bs;
    const int tid = threadIdx.x;
    if (tid < 128) rowreg[tid] = reg_indx[c.row0 + tid];
#pragma unroll
    for (int q = 0; q < 8; ++q) redmax[tid + q * 256] = 0u;
    f32x4 acc[4][4];
#pragma unroll
    for (int i = 0; i < 4; ++i)
#pragma unroll
        for (int j = 0; j < 4; ++j) acc[i][j] = (f32x4)0.f;
    GEMM_KLOOP(smA, smB, c, acc)   // barriers inside make the init visible
    float bb[4];
#pragma unroll
    for (int j = 0; j < 4; ++j) bb[j] = bias[c.col0 + c.wc * 64 + j * 16 + (c.lane & 15)];
#pragma unroll
    for (int i = 0; i < 4; ++i) {
        const int lrow = c.wr * 64 + i * 16 + ((c.lane >> 4) << 2);
#pragma unroll
        for (int j = 0; j < 4; ++j) {
            const int lcol = c.wc * 64 + j * 16 + (c.lane & 15);
#pragma unroll
            for (int ii = 0; ii < 4; ++ii) {
                const float v = fmaxf(acc[i][j][ii] + bb[j], 0.f);
                atomicMax(&redmax[rowreg[lrow + ii] * 128 + lcol], __float_as_uint(v));
            }
        }
    }
    __syncthreads();
    const int b = c.row0 >> 12;
#pragma unroll
    for (int q = 0; q < 8; ++q) {
        const int idx = tid + q * 256;
        const int r = idx >> 7, col = idx & 127;
        atomicMax((unsigned*)&regvec[(((size_t)b * R + r) << 9) + c.col0 + col],
                  redmax[idx]);
    }
}

// ---------------- output: middle slice only (x/g written by occ) ------------
__global__ __launch_bounds__(256) void out_mid_kernel(
    const float* __restrict__ regvec, const int* __restrict__ reg_indx,
    float* __restrict__ out)
{
    const int row = blockIdx.x * 2 + (threadIdx.x >> 7);
    const int t = threadIdx.x & 127;
    const int b = row >> 12;
    const int r = reg_indx[row];
    const float4* rv = (const float4*)(regvec + ((size_t)b * R + r) * D);
    float4* o = (float4*)(out + (size_t)row * 3 * D + D);
    o[t] = rv[t];
}

// ---------------- fallback full output assembly (carve path) ----------------
__global__ __launch_bounds__(256) void out_full_kernel(
    const float* __restrict__ x, const float* __restrict__ g,
    const float* __restrict__ regvec, const int* __restrict__ reg_indx,
    float* __restrict__ out)
{
    const int row = blockIdx.x * 2 + (threadIdx.x >> 7);
    const int t = threadIdx.x & 127;
    const int b = row >> 12;
    const int r = reg_indx[row];
    const float4* xr = (const float4*)(x + (size_t)row * D);
    const float4* rv = (const float4*)(regvec + ((size_t)b * R + r) * D);
    const float4* gr = (const float4*)(g + (size_t)b * D);
    float4* o = (float4*)(out + (size_t)row * 3 * D);
    o[t]       = xr[t];
    o[128 + t] = rv[t];
    o[256 + t] = gr[t];
}

extern "C" void kernel_launch(void* const* d_in, const int* in_sizes, int n_in,
                              void* d_out, int out_size, void* d_ws, size_t ws_size,
                              hipStream_t stream)
{
    (void)in_sizes; (void)n_in; (void)out_size;
    const float* x     = (const float*)d_in[0];
    const float* g_vec = (const float*)d_in[1];
    const float* occ_w = (const float*)d_in[2];
    const float* occ_b = (const float*)d_in[3];
    const float* w1    = (const float*)d_in[4];
    const float* b1    = (const float*)d_in[5];
    const float* w2    = (const float*)d_in[6];
    const float* b2    = (const float*)d_in[7];
    float* out = (float*)d_out;

    char* ws = (char*)d_ws;
    size_t off = 0;
    auto alloc = [&](size_t bytes) {
        char* p = ws + off; off = (off + bytes + 255) & ~(size_t)255; return p;
    };
    int*    reg_indx  = (int*)alloc((size_t)M * 4);
    float*  reg_logit = (float*)alloc((size_t)M * 4);
    int*    pcnt      = (int*)alloc(64 * R * 4);
    double* psum      = (double*)alloc(64 * R * 8);
    int*    counts    = (int*)alloc(B * R * 4);
    float*  regvec    = (float*)alloc((size_t)B * R * D * 4);

    const size_t xbB = (size_t)M * D * 2, wB = (size_t)D * D * 2;
    ushort *xb, *h1, *w1t, *w2t;
    int fused;                        // 1: ws holds intermediates, occ writes out.x/g
    if (ws_size >= off + 2 * xbB + 2 * wB + 1024) {
        fused = 1;
        xb  = (ushort*)alloc(xbB);
        h1  = (ushort*)alloc(xbB);
        w1t = (ushort*)alloc(wB);
        w2t = (ushort*)alloc(wB);
    } else {                          // carve from d_out; fully rewritten later
        fused = 0;
        char* o = (char*)d_out;
        xb  = (ushort*)o;
        h1  = (ushort*)(o + xbB);
        w1t = (ushort*)(o + 2 * xbB);
        w2t = (ushort*)(o + 2 * xbB + wB);
    }

    hipLaunchKernelGGL(occ_kernel, dim3(M / 64), dim3(256), 0, stream,
                       x, occ_w, occ_b, g_vec, reg_indx, reg_logit, xb, out, fused);
    hipLaunchKernelGGL(wtrans_kernel, dim3(512), dim3(256), 0, stream,
                       w1, w2, w1t, w2t);
    hipLaunchKernelGGL(loss_part_kernel, dim3(64), dim3(256), 0, stream,
                       reg_indx, reg_logit, pcnt, psum);
    hipLaunchKernelGGL(loss_final_kernel, dim3(1), dim3(128), 0, stream,
                       pcnt, psum, counts, out + OUT_ELEMS);
    hipLaunchKernelGGL(init_regvec_c2_kernel, dim3(16), dim3(256), 0, stream,
                       b1, w2, b2, counts, regvec);
    hipLaunchKernelGGL(gemm_mfma1, dim3((M / 128) * (D / 128)), dim3(256), 0, stream,
                       xb, w1t, b1, h1);
    hipLaunchKernelGGL(gemm_mfma2, dim3((M / 128) * (D / 128)), dim3(256), 0, stream,
                       h1, w2t, b2, reg_indx, regvec);
    if (fused) {
        hipLaunchKernelGGL(out_mid_kernel, dim3(M / 2), dim3(256), 0, stream,
                           regvec, reg_indx, out);
    } else {
        hipLaunchKernelGGL(out_full_kernel, dim3(M / 2), dim3(256), 0, stream,
                           x, g_vec, regvec, reg_indx, out);
    }
}

// Round 15
// 149.292 us; speedup vs baseline: 2.0436x; 1.0222x over previous
//
#include <hip/hip_runtime.h>
#include <cstdint>
#include <cstddef>

constexpr int B = 8, S = 4096, D = 512, R = 16;
constexpr int M = B * S;                         // 32768 rows
constexpr long long OUT_ELEMS = (long long)M * 3 * D;  // 50331648

typedef short short8 __attribute__((ext_vector_type(8)));
typedef short short4v __attribute__((ext_vector_type(4)));
typedef float f32x4 __attribute__((ext_vector_type(4)));

__device__ __forceinline__ ushort f2bf(float f) {
    union { float f; unsigned u; } v; v.f = f;
    return (ushort)((v.u + 0x7fffu + ((v.u >> 16) & 1u)) >> 16);
}

__device__ __forceinline__ void gload_lds16(const void* g, void* l) {
    __builtin_amdgcn_global_load_lds(
        (const __attribute__((address_space(1))) void*)g,
        (__attribute__((address_space(3))) void*)l, 16, 0, 0);
}

// ---------------- occ (LDS-shared, r14-proven) + g-interleave + wtrans ------
// blocks [0,512): occ.  4 waves x 16 rows.  wT staged once (ONE barrier,
//   before any global stores).  Per 64-k chunk: wave stages x[16][64] from
//   registers (same regs feed out.x + xb + out.g stores -> the g tail is
//   gone, overlapped with compute); wave-local lgkmcnt only, no barriers.
//   Lane (rowgrp, logit) accumulates 4 rows' logit per chunk from LDS.
//   Logit math BIT-IDENTICAL to round 14 -> same argmax, same absmax.
// blocks [512,1024): w1/w2 transpose + bf16 convert.
__global__ __launch_bounds__(256) void occ_kernel(
    const float* __restrict__ x, const float* __restrict__ occ_w,
    const float* __restrict__ occ_b, const float* __restrict__ g_vec,
    int* __restrict__ reg_indx, float* __restrict__ reg_logit,
    ushort* __restrict__ xb,
    const float* __restrict__ w1, const float* __restrict__ w2,
    ushort* __restrict__ w1t, ushort* __restrict__ w2t,
    float* __restrict__ out, int writeOut)
{
    __shared__ float wT[16][516];      // wT[logit][k], 33KB
    __shared__ float xs[4][16][68];    // per-wave [16 rows][64 k], 17.4KB
    const int tid = threadIdx.x;
    if (blockIdx.x >= 512) {                      // ---- wtrans branch ----
        float (*tile)[33] = reinterpret_cast<float(*)[33]>(&wT[0][0]);
        const int wb = blockIdx.x - 512;          // 0..511
        const float* w = (wb >> 8) ? w2 : w1;
        ushort* wt = (wb >> 8) ? w2t : w1t;
        const int rest = wb & 255;
        const int n0 = (rest & 15) * 32, k0 = (rest >> 4) * 32;
        const int tx = tid & 31, ty = tid >> 5;
#pragma unroll
        for (int qq = 0; qq < 4; ++qq)
            tile[ty * 4 + qq][tx] = w[(size_t)(k0 + ty * 4 + qq) * D + n0 + tx];
        __syncthreads();
#pragma unroll
        for (int qq = 0; qq < 4; ++qq)
            wt[(size_t)(n0 + ty * 4 + qq) * D + k0 + tx] = f2bf(tile[tx][ty * 4 + qq]);
        return;
    }
    // ---- occ branch ----
    for (int idx = tid; idx < D * R; idx += 256)   // wT[r][k] = occ_w[k*16+r]
        wT[idx & 15][idx >> 4] = occ_w[idx];
    __syncthreads();                   // ONLY barrier; no global stores yet
    const int wave = tid >> 6, lane = tid & 63;
    const int logit = lane & 15, rowgrp = lane >> 4;
    const int row0 = blockIdx.x * 64 + wave * 16;  // wave's 16 rows
    const int bat = row0 >> 12;
    float (*xw)[68] = xs[wave];
    const float* xbase = x + (size_t)row0 * D;
    const int kq4 = (lane & 15) * 4;               // staging col for this lane
    double acc[4] = {0.0, 0.0, 0.0, 0.0};
    float4 st[4];
#pragma unroll
    for (int i = 0; i < 4; ++i)        // prologue: chunk 0 (rows i*4+rowgrp)
        st[i] = *(const float4*)&xbase[(size_t)(i * 4 + rowgrp) * D + kq4];
#pragma unroll 1
    for (int c = 0; c < 8; ++c) {
        const int k0 = c * 64;
        float4 nx[4];
        if (c < 7) {
#pragma unroll
            for (int i = 0; i < 4; ++i)
                nx[i] = *(const float4*)&xbase[(size_t)(i * 4 + rowgrp) * D + k0 + 64 + kq4];
        }
        // copy-out + LDS write of current chunk (from held registers)
        asm volatile("s_waitcnt lgkmcnt(0)" ::: "memory");  // reads of c-1 done
        float4 gv;
        if (writeOut)
            gv = *(const float4*)&g_vec[(size_t)bat * D + k0 + kq4];
#pragma unroll
        for (int i = 0; i < 4; ++i) {
            const int rl = i * 4 + rowgrp;
            const int row = row0 + rl;
            short4v pk;
            pk[0] = (short)f2bf(st[i].x); pk[1] = (short)f2bf(st[i].y);
            pk[2] = (short)f2bf(st[i].z); pk[3] = (short)f2bf(st[i].w);
            *(short4v*)&xb[(size_t)row * D + k0 + kq4] = pk;
            if (writeOut) {
                float* orow = out + (size_t)row * 3 * D;
                *(float4*)&orow[k0 + kq4] = st[i];           // x slice
                *(float4*)&orow[2 * D + k0 + kq4] = gv;      // g slice
            }
            *(float4*)&xw[rl][kq4] = st[i];
        }
        asm volatile("s_waitcnt lgkmcnt(0)" ::: "memory");  // writes visible
        // compute: 16 k-quads; x broadcast across 16 lanes, w 2-way banks
#pragma unroll 4
        for (int k = 0; k < 64; k += 4) {
            const f32x4 wv = *(const f32x4*)&wT[logit][k0 + k];
#pragma unroll
            for (int j = 0; j < 4; ++j) {
                const f32x4 xv = *(const f32x4*)&xw[rowgrp * 4 + j][k];
                acc[j] += (double)xv[0] * (double)wv[0];
                acc[j] += (double)xv[1] * (double)wv[1];
                acc[j] += (double)xv[2] * (double)wv[2];
                acc[j] += (double)xv[3] * (double)wv[3];
            }
        }
#pragma unroll
        for (int i = 0; i < 4; ++i) st[i] = nx[i];
    }
    // ---- epilogue: per-row argmax within each 16-lane group ----
    const double bias = (double)occ_b[logit];
#pragma unroll
    for (int j = 0; j < 4; ++j) {
        const double s = acc[j] + bias;            // lane's logit for its row
        double mv = s; int mi = logit;
#pragma unroll
        for (int off = 1; off < 16; off <<= 1) {
            const double ov = __shfl_xor(mv, off, 64);
            const int    oi = __shfl_xor(mi, off, 64);
            if (ov > mv || (ov == mv && oi < mi)) { mv = ov; mi = oi; }
        }
        float ef = expf((float)(s - mv));
#pragma unroll
        for (int off = 1; off < 16; off <<= 1) ef += __shfl_xor(ef, off, 64);
        if (logit == 0) {
            const int row = row0 + rowgrp * 4 + j;
            reg_indx[row] = mi; reg_logit[row] = 1.0f / ef;
        }
    }
}

// ---------------- loss partials: 64 blocks = (batch, chunk-of-512-rows) ----
__global__ __launch_bounds__(256) void loss_part_kernel(
    const int* __restrict__ reg_indx, const float* __restrict__ reg_logit,
    int* __restrict__ pcnt, double* __restrict__ psum)
{
    const int b = blockIdx.x >> 3, c = blockIdx.x & 7;
    const int t = threadIdx.x;
    __shared__ double ssum[R][257];
    __shared__ int    scnt[R][257];
#pragma unroll
    for (int r = 0; r < R; ++r) { ssum[r][t] = 0.0; scnt[r][t] = 0; }
    __syncthreads();
    const int base = b * S + c * 512;
    for (int s = t; s < 512; s += 256) {
        const int r = reg_indx[base + s];
        ssum[r][t] += (double)reg_logit[base + s];
        scnt[r][t] += 1;
    }
    __syncthreads();
    for (int off = 128; off > 0; off >>= 1) {
        if (t < off) {
#pragma unroll
            for (int r = 0; r < R; ++r) {
                ssum[r][t] += ssum[r][t + off];
                scnt[r][t] += scnt[r][t + off];
            }
        }
        __syncthreads();
    }
    if (t < R) {
        psum[blockIdx.x * R + t] = ssum[t][0];
        pcnt[blockIdx.x * R + t] = scnt[t][0];
    }
}

// ---------------- finalize: blocks 0-15 = c2+regvec init (counts inline);
//                  block 16 = scalar loss ------------------------------------
__global__ __launch_bounds__(256) void finalize_kernel(
    const int* __restrict__ pcnt, const double* __restrict__ psum,
    const float* __restrict__ b1, const float* __restrict__ w2,
    const float* __restrict__ b2, float* __restrict__ regvec,
    float* __restrict__ out_loss)
{
    const int t = threadIdx.x;
    if (blockIdx.x == 16) {                        // ---- loss branch ----
        __shared__ double m2[128];
        if (t < 128) {
            const int b = t >> 4, r = t & 15;
            double s = 0.0;
#pragma unroll
            for (int c = 0; c < 8; ++c) s += psum[(b * 8 + c) * R + r];
            const double mean = s / (double)S;
            m2[t] = mean * mean;
        }
        __syncthreads();
        if (t == 0) {
            double tot = 0.0;
            for (int i = 0; i < 128; ++i) tot += m2[i];
            *out_loss = (float)(tot / (double)B);
        }
        return;
    }
    __shared__ float c1[D];
    __shared__ float part[8][33];
    __shared__ int cnts[128];
    c1[t]       = fmaxf(b1[t], 0.f);
    c1[t + 256] = fmaxf(b1[t + 256], 0.f);
    if (t < 128) {                                 // counts from pcnt
        int c = 0;
#pragma unroll
        for (int q = 0; q < 8; ++q) c += pcnt[((t >> 4) * 8 + q) * R + (t & 15)];
        cnts[t] = c;
    }
    __syncthreads();
    const int dl = t & 31, kg = t >> 5;            // 8 k-groups x 64 k
    const int d = blockIdx.x * 32 + dl;
    float p = 0.f;
    for (int k = kg * 64; k < kg * 64 + 64; ++k)
        p += c1[k] * w2[(size_t)k * D + d];
    part[kg][dl] = p;
    __syncthreads();
    if (t < 32) {
        const int dd = blockIdx.x * 32 + t;
        float acc = b2[dd];
#pragma unroll
        for (int kk = 0; kk < 8; ++kk) acc += part[kk][t];
        const float c2d = fmaxf(acc, 0.f);
        for (int br = 0; br < B * R; ++br)
            regvec[(size_t)br * D + dd] = (cnts[br] < S) ? c2d : 0.f;
    }
}

// ================= MFMA GEMM: 128x128 tile, 4 waves, 16x16x32 bf16 ==========
struct GemmCtx {
    int row0, col0, wave, lane, wr, wc;
    unsigned dsto[2];
    const ushort *aSrc[2], *bSrc[2];
    unsigned aOff[4], bOff[4];
};

__device__ __forceinline__ void gemm_setup(
    GemmCtx& c, const ushort* Ab, const ushort* Bt)
{
    const int tid = threadIdx.x;
    c.wave = tid >> 6; c.lane = tid & 63;
    c.wr = c.wave >> 1; c.wc = c.wave & 1;
    // bijective XCD swizzle over nwg=1024 (8 XCDs x 128 chunks)
    const int orig = blockIdx.x;
    const int wg = (orig & 7) * 128 + (orig >> 3);
    c.row0 = (wg >> 2) * 128;   // 256 mtiles
    c.col0 = (wg & 3) * 128;    // 4 ntiles
#pragma unroll
    for (int q = 0; q < 2; ++q) {
        const unsigned o = (unsigned)(c.wave * 2 + q) * 1024u + (unsigned)c.lane * 16u;
        c.dsto[q] = (unsigned)(c.wave * 2 + q) * 1024u;
        const unsigned r  = ((o >> 7) << 1) | (((o >> 6) ^ (o >> 8)) & 1u);
        const unsigned kg = ((o >> 4) & 3u) ^ (r & 3u);
        c.aSrc[q] = Ab + (size_t)(c.row0 + r) * D + kg * 8;
        c.bSrc[q] = Bt + (size_t)(c.col0 + r) * D + kg * 8;
    }
#pragma unroll
    for (int i = 0; i < 4; ++i) {
        const unsigned kg = (unsigned)(c.lane >> 4);
        unsigned r = (unsigned)(c.wr * 64 + i * 16 + (c.lane & 15));
        c.aOff[i] = ((r << 6) + (kg << 4)) ^ ((r & 7u) << 4);
        r = (unsigned)(c.wc * 64 + i * 16 + (c.lane & 15));
        c.bOff[i] = ((r << 6) + (kg << 4)) ^ ((r & 7u) << 4);
    }
}

#define STAGE4(ctx, smA, smB, bufofs, kt)                                 \
    gload_lds16(ctx.aSrc[0] + (kt), smA + (bufofs) + ctx.dsto[0]);        \
    gload_lds16(ctx.aSrc[1] + (kt), smA + (bufofs) + ctx.dsto[1]);        \
    gload_lds16(ctx.bSrc[0] + (kt), smB + (bufofs) + ctx.dsto[0]);        \
    gload_lds16(ctx.bSrc[1] + (kt), smB + (bufofs) + ctx.dsto[1]);

#define GEMM_KLOOP(smA, smB, ctx, acc)                                         \
    STAGE4(ctx, smA, smB, 0, 0)                                                \
    __syncthreads();                                                           \
    _Pragma("unroll")                                                          \
    for (int t = 0; t < 16; ++t) {                                             \
        const int co = (t & 1) * 8192;                                         \
        if (t < 15) { STAGE4(ctx, smA, smB, co ^ 8192, (t + 1) * 32) }         \
        short8 a[4], b[4];                                                     \
        _Pragma("unroll")                                                      \
        for (int i = 0; i < 4; ++i)                                            \
            a[i] = *(const short8*)(smA + co + ctx.aOff[i]);                   \
        _Pragma("unroll")                                                      \
        for (int j = 0; j < 4; ++j)                                            \
            b[j] = *(const short8*)(smB + co + ctx.bOff[j]);                   \
        _Pragma("unroll")                                                      \
        for (int i = 0; i < 4; ++i)                                            \
            _Pragma("unroll")                                                  \
            for (int j = 0; j < 4; ++j)                                        \
                acc[i][j] = __builtin_amdgcn_mfma_f32_16x16x32_bf16(           \
                    a[i], b[j], acc[i][j], 0, 0, 0);                           \
        __syncthreads();                                                       \
    }

// GEMM1: h1 = relu(xb @ w1t^T + b1), bf16 out
__global__ __launch_bounds__(256, 2) void gemm_mfma1(
    const ushort* __restrict__ Ab, const ushort* __restrict__ Bt,
    const float* __restrict__ bias, ushort* __restrict__ H)
{
    __shared__ ushort As[8192];
    __shared__ ushort Bs[8192];
    GemmCtx c; gemm_setup(c, Ab, Bt);
    char* smA = (char*)As; char* smB = (char*)Bs;
    f32x4 acc[4][4];
#pragma unroll
    for (int i = 0; i < 4; ++i)
#pragma unroll
        for (int j = 0; j < 4; ++j) acc[i][j] = (f32x4)0.f;
    GEMM_KLOOP(smA, smB, c, acc)
    float bb[4];
#pragma unroll
    for (int j = 0; j < 4; ++j) bb[j] = bias[c.col0 + c.wc * 64 + j * 16 + (c.lane & 15)];
#pragma unroll
    for (int i = 0; i < 4; ++i) {
        const int row = c.row0 + c.wr * 64 + i * 16 + ((c.lane >> 4) << 2);
#pragma unroll
        for (int j = 0; j < 4; ++j) {
            const int col = c.col0 + c.wc * 64 + j * 16 + (c.lane & 15);
#pragma unroll
            for (int ii = 0; ii < 4; ++ii) {
                const float v = fmaxf(acc[i][j][ii] + bb[j], 0.f);
                H[(size_t)(row + ii) * D + col] = f2bf(v);
            }
        }
    }
}

// GEMM2: v = relu(h1 @ w2t^T + b2); segmented max by reg_indx into regvec
__global__ __launch_bounds__(256, 2) void gemm_mfma2(
    const ushort* __restrict__ Ab, const ushort* __restrict__ Bt,
    const float* __restrict__ bias, const int* __restrict__ reg_indx,
    float* __restrict__ regvec)
{
    __shared__ ushort As[8192];
    __shared__ ushort Bs[8192];
    __shared__ unsigned redmax[R * 128];
    __shared__ int rowreg[128];
    GemmCtx c; gemm_setup(c, Ab, Bt);
    char* smA = (char*)As; char* smB = (char*)Bs;
    const int tid = threadIdx.x;
    if (tid < 128) rowreg[tid] = reg_indx[c.row0 + tid];
#pragma unroll
    for (int q = 0; q < 8; ++q) redmax[tid + q * 256] = 0u;
    f32x4 acc[4][4];
#pragma unroll
    for (int i = 0; i < 4; ++i)
#pragma unroll
        for (int j = 0; j < 4; ++j) acc[i][j] = (f32x4)0.f;
    GEMM_KLOOP(smA, smB, c, acc)   // barriers inside make the init visible
    float bb[4];
#pragma unroll
    for (int j = 0; j < 4; ++j) bb[j] = bias[c.col0 + c.wc * 64 + j * 16 + (c.lane & 15)];
#pragma unroll
    for (int i = 0; i < 4; ++i) {
        const int lrow = c.wr * 64 + i * 16 + ((c.lane >> 4) << 2);
#pragma unroll
        for (int j = 0; j < 4; ++j) {
            const int lcol = c.wc * 64 + j * 16 + (c.lane & 15);
#pragma unroll
            for (int ii = 0; ii < 4; ++ii) {
                const float v = fmaxf(acc[i][j][ii] + bb[j], 0.f);
                atomicMax(&redmax[rowreg[lrow + ii] * 128 + lcol], __float_as_uint(v));
            }
        }
    }
    __syncthreads();
    const int b = c.row0 >> 12;
#pragma unroll
    for (int q = 0; q < 8; ++q) {
        const int idx = tid + q * 256;
        const int r = idx >> 7, col = idx & 127;
        atomicMax((unsigned*)&regvec[(((size_t)b * R + r) << 9) + c.col0 + col],
                  redmax[idx]);
    }
}

// ---------------- output: middle slice only (x/g written by occ) ------------
__global__ __launch_bounds__(256) void out_mid_kernel(
    const float* __restrict__ regvec, const int* __restrict__ reg_indx,
    float* __restrict__ out)
{
    const int row = blockIdx.x * 2 + (threadIdx.x >> 7);
    const int t = threadIdx.x & 127;
    const int b = row >> 12;
    const int r = reg_indx[row];
    const float4* rv = (const float4*)(regvec + ((size_t)b * R + r) * D);
    float4* o = (float4*)(out + (size_t)row * 3 * D + D);
    o[t] = rv[t];
}

// ---------------- fallback full output assembly (carve path) ----------------
__global__ __launch_bounds__(256) void out_full_kernel(
    const float* __restrict__ x, const float* __restrict__ g,
    const float* __restrict__ regvec, const int* __restrict__ reg_indx,
    float* __restrict__ out)
{
    const int row = blockIdx.x * 2 + (threadIdx.x >> 7);
    const int t = threadIdx.x & 127;
    const int b = row >> 12;
    const int r = reg_indx[row];
    const float4* xr = (const float4*)(x + (size_t)row * D);
    const float4* rv = (const float4*)(regvec + ((size_t)b * R + r) * D);
    const float4* gr = (const float4*)(g + (size_t)b * D);
    float4* o = (float4*)(out + (size_t)row * 3 * D);
    o[t]       = xr[t];
    o[128 + t] = rv[t];
    o[256 + t] = gr[t];
}

extern "C" void kernel_launch(void* const* d_in, const int* in_sizes, int n_in,
                              void* d_out, int out_size, void* d_ws, size_t ws_size,
                              hipStream_t stream)
{
    (void)in_sizes; (void)n_in; (void)out_size;
    const float* x     = (const float*)d_in[0];
    const float* g_vec = (const float*)d_in[1];
    const float* occ_w = (const float*)d_in[2];
    const float* occ_b = (const float*)d_in[3];
    const float* w1    = (const float*)d_in[4];
    const float* b1    = (const float*)d_in[5];
    const float* w2    = (const float*)d_in[6];
    const float* b2    = (const float*)d_in[7];
    float* out = (float*)d_out;

    char* ws = (char*)d_ws;
    size_t off = 0;
    auto alloc = [&](size_t bytes) {
        char* p = ws + off; off = (off + bytes + 255) & ~(size_t)255; return p;
    };
    int*    reg_indx  = (int*)alloc((size_t)M * 4);
    float*  reg_logit = (float*)alloc((size_t)M * 4);
    int*    pcnt      = (int*)alloc(64 * R * 4);
    double* psum      = (double*)alloc(64 * R * 8);
    float*  regvec    = (float*)alloc((size_t)B * R * D * 4);

    const size_t xbB = (size_t)M * D * 2, wB = (size_t)D * D * 2;
    ushort *xb, *h1, *w1t, *w2t;
    int fused;                        // 1: ws holds intermediates, occ writes out.x/g
    if (ws_size >= off + 2 * xbB + 2 * wB + 1024) {
        fused = 1;
        xb  = (ushort*)alloc(xbB);
        h1  = (ushort*)alloc(xbB);
        w1t = (ushort*)alloc(wB);
        w2t = (ushort*)alloc(wB);
    } else {                          // carve from d_out; fully rewritten later
        fused = 0;
        char* o = (char*)d_out;
        xb  = (ushort*)o;
        h1  = (ushort*)(o + xbB);
        w1t = (ushort*)(o + 2 * xbB);
        w2t = (ushort*)(o + 2 * xbB + wB);
    }

    hipLaunchKernelGGL(occ_kernel, dim3(1024), dim3(256), 0, stream,
                       x, occ_w, occ_b, g_vec, reg_indx, reg_logit, xb,
                       w1, w2, w1t, w2t, out, fused);
    hipLaunchKernelGGL(loss_part_kernel, dim3(64), dim3(256), 0, stream,
                       reg_indx, reg_logit, pcnt, psum);
    hipLaunchKernelGGL(finalize_kernel, dim3(17), dim3(256), 0, stream,
                       pcnt, psum, b1, w2, b2, regvec, out + OUT_ELEMS);
    hipLaunchKernelGGL(gemm_mfma1, dim3((M / 128) * (D / 128)), dim3(256), 0, stream,
                       xb, w1t, b1, h1);
    hipLaunchKernelGGL(gemm_mfma2, dim3((M / 128) * (D / 128)), dim3(256), 0, stream,
                       h1, w2t, b2, reg_indx, regvec);
    if (fused) {
        hipLaunchKernelGGL(out_mid_kernel, dim3(M / 2), dim3(256), 0, stream,
                           regvec, reg_indx, out);
    } else {
        hipLaunchKernelGGL(out_full_kernel, dim3(M / 2), dim3(256), 0, stream,
                           x, g_vec, regvec, reg_indx, out);
    }
}

// Round 16
// 149.066 us; speedup vs baseline: 2.0467x; 1.0015x over previous
//
#include <hip/hip_runtime.h>
#include <cstdint>
#include <cstddef>

constexpr int B = 8, S = 4096, D = 512, R = 16;
constexpr int M = B * S;                         // 32768 rows
constexpr long long OUT_ELEMS = (long long)M * 3 * D;  // 50331648

typedef short short8 __attribute__((ext_vector_type(8)));
typedef short short4v __attribute__((ext_vector_type(4)));
typedef float f32x4 __attribute__((ext_vector_type(4)));

__device__ __forceinline__ ushort f2bf(float f) {
    union { float f; unsigned u; } v; v.f = f;
    return (ushort)((v.u + 0x7fffu + ((v.u >> 16) & 1u)) >> 16);
}

__device__ __forceinline__ void gload_lds16(const void* g, void* l) {
    __builtin_amdgcn_global_load_lds(
        (const __attribute__((address_space(1))) void*)g,
        (__attribute__((address_space(3))) void*)l, 16, 0, 0);
}

// ---------------- occ (LDS-shared) + g-interleave + wtrans (r15-proven) -----
__global__ __launch_bounds__(256) void occ_kernel(
    const float* __restrict__ x, const float* __restrict__ occ_w,
    const float* __restrict__ occ_b, const float* __restrict__ g_vec,
    int* __restrict__ reg_indx, float* __restrict__ reg_logit,
    ushort* __restrict__ xb,
    const float* __restrict__ w1, const float* __restrict__ w2,
    ushort* __restrict__ w1t, ushort* __restrict__ w2t,
    float* __restrict__ out, int writeOut)
{
    __shared__ float wT[16][516];      // wT[logit][k], 33KB
    __shared__ float xs[4][16][68];    // per-wave [16 rows][64 k], 17.4KB
    const int tid = threadIdx.x;
    if (blockIdx.x >= 512) {                      // ---- wtrans branch ----
        float (*tile)[33] = reinterpret_cast<float(*)[33]>(&wT[0][0]);
        const int wb = blockIdx.x - 512;          // 0..511
        const float* w = (wb >> 8) ? w2 : w1;
        ushort* wt = (wb >> 8) ? w2t : w1t;
        const int rest = wb & 255;
        const int n0 = (rest & 15) * 32, k0 = (rest >> 4) * 32;
        const int tx = tid & 31, ty = tid >> 5;
#pragma unroll
        for (int qq = 0; qq < 4; ++qq)
            tile[ty * 4 + qq][tx] = w[(size_t)(k0 + ty * 4 + qq) * D + n0 + tx];
        __syncthreads();
#pragma unroll
        for (int qq = 0; qq < 4; ++qq)
            wt[(size_t)(n0 + ty * 4 + qq) * D + k0 + tx] = f2bf(tile[tx][ty * 4 + qq]);
        return;
    }
    // ---- occ branch ----
    for (int idx = tid; idx < D * R; idx += 256)   // wT[r][k] = occ_w[k*16+r]
        wT[idx & 15][idx >> 4] = occ_w[idx];
    __syncthreads();                   // ONLY barrier; no global stores yet
    const int wave = tid >> 6, lane = tid & 63;
    const int logit = lane & 15, rowgrp = lane >> 4;
    const int row0 = blockIdx.x * 64 + wave * 16;  // wave's 16 rows
    const int bat = row0 >> 12;
    float (*xw)[68] = xs[wave];
    const float* xbase = x + (size_t)row0 * D;
    const int kq4 = (lane & 15) * 4;               // staging col for this lane
    double acc[4] = {0.0, 0.0, 0.0, 0.0};
    float4 st[4];
#pragma unroll
    for (int i = 0; i < 4; ++i)        // prologue: chunk 0 (rows i*4+rowgrp)
        st[i] = *(const float4*)&xbase[(size_t)(i * 4 + rowgrp) * D + kq4];
#pragma unroll 1
    for (int c = 0; c < 8; ++c) {
        const int k0 = c * 64;
        float4 nx[4];
        if (c < 7) {
#pragma unroll
            for (int i = 0; i < 4; ++i)
                nx[i] = *(const float4*)&xbase[(size_t)(i * 4 + rowgrp) * D + k0 + 64 + kq4];
        }
        // copy-out + LDS write of current chunk (from held registers)
        asm volatile("s_waitcnt lgkmcnt(0)" ::: "memory");  // reads of c-1 done
        float4 gv;
        if (writeOut)
            gv = *(const float4*)&g_vec[(size_t)bat * D + k0 + kq4];
#pragma unroll
        for (int i = 0; i < 4; ++i) {
            const int rl = i * 4 + rowgrp;
            const int row = row0 + rl;
            short4v pk;
            pk[0] = (short)f2bf(st[i].x); pk[1] = (short)f2bf(st[i].y);
            pk[2] = (short)f2bf(st[i].z); pk[3] = (short)f2bf(st[i].w);
            *(short4v*)&xb[(size_t)row * D + k0 + kq4] = pk;
            if (writeOut) {
                float* orow = out + (size_t)row * 3 * D;
                *(float4*)&orow[k0 + kq4] = st[i];           // x slice
                *(float4*)&orow[2 * D + k0 + kq4] = gv;      // g slice
            }
            *(float4*)&xw[rl][kq4] = st[i];
        }
        asm volatile("s_waitcnt lgkmcnt(0)" ::: "memory");  // writes visible
        // compute: 16 k-quads; x broadcast across 16 lanes, w 2-way banks
#pragma unroll 4
        for (int k = 0; k < 64; k += 4) {
            const f32x4 wv = *(const f32x4*)&wT[logit][k0 + k];
#pragma unroll
            for (int j = 0; j < 4; ++j) {
                const f32x4 xv = *(const f32x4*)&xw[rowgrp * 4 + j][k];
                acc[j] += (double)xv[0] * (double)wv[0];
                acc[j] += (double)xv[1] * (double)wv[1];
                acc[j] += (double)xv[2] * (double)wv[2];
                acc[j] += (double)xv[3] * (double)wv[3];
            }
        }
#pragma unroll
        for (int i = 0; i < 4; ++i) st[i] = nx[i];
    }
    // ---- epilogue: per-row argmax within each 16-lane group ----
    const double bias = (double)occ_b[logit];
#pragma unroll
    for (int j = 0; j < 4; ++j) {
        const double s = acc[j] + bias;            // lane's logit for its row
        double mv = s; int mi = logit;
#pragma unroll
        for (int off = 1; off < 16; off <<= 1) {
            const double ov = __shfl_xor(mv, off, 64);
            const int    oi = __shfl_xor(mi, off, 64);
            if (ov > mv || (ov == mv && oi < mi)) { mv = ov; mi = oi; }
        }
        float ef = expf((float)(s - mv));
#pragma unroll
        for (int off = 1; off < 16; off <<= 1) ef += __shfl_xor(ef, off, 64);
        if (logit == 0) {
            const int row = row0 + rowgrp * 4 + j;
            reg_indx[row] = mi; reg_logit[row] = 1.0f / ef;
        }
    }
}

// ---------------- loss partials: 64 blocks = (batch, chunk-of-512-rows) ----
__global__ __launch_bounds__(256) void loss_part_kernel(
    const int* __restrict__ reg_indx, const float* __restrict__ reg_logit,
    int* __restrict__ pcnt, double* __restrict__ psum)
{
    const int b = blockIdx.x >> 3, c = blockIdx.x & 7;
    const int t = threadIdx.x;
    __shared__ double ssum[R][257];
    __shared__ int    scnt[R][257];
#pragma unroll
    for (int r = 0; r < R; ++r) { ssum[r][t] = 0.0; scnt[r][t] = 0; }
    __syncthreads();
    const int base = b * S + c * 512;
    for (int s = t; s < 512; s += 256) {
        const int r = reg_indx[base + s];
        ssum[r][t] += (double)reg_logit[base + s];
        scnt[r][t] += 1;
    }
    __syncthreads();
    for (int off = 128; off > 0; off >>= 1) {
        if (t < off) {
#pragma unroll
            for (int r = 0; r < R; ++r) {
                ssum[r][t] += ssum[r][t + off];
                scnt[r][t] += scnt[r][t + off];
            }
        }
        __syncthreads();
    }
    if (t < R) {
        psum[blockIdx.x * R + t] = ssum[t][0];
        pcnt[blockIdx.x * R + t] = scnt[t][0];
    }
}

// ---------------- finalize: blocks 0-15 = c2+regvec init (counts inline);
//                  block 16 = scalar loss ------------------------------------
__global__ __launch_bounds__(256) void finalize_kernel(
    const int* __restrict__ pcnt, const double* __restrict__ psum,
    const float* __restrict__ b1, const float* __restrict__ w2,
    const float* __restrict__ b2, float* __restrict__ regvec,
    float* __restrict__ out_loss)
{
    const int t = threadIdx.x;
    if (blockIdx.x == 16) {                        // ---- loss branch ----
        __shared__ double m2[128];
        if (t < 128) {
            const int b = t >> 4, r = t & 15;
            double s = 0.0;
#pragma unroll
            for (int c = 0; c < 8; ++c) s += psum[(b * 8 + c) * R + r];
            const double mean = s / (double)S;
            m2[t] = mean * mean;
        }
        __syncthreads();
        if (t == 0) {
            double tot = 0.0;
            for (int i = 0; i < 128; ++i) tot += m2[i];
            *out_loss = (float)(tot / (double)B);
        }
        return;
    }
    __shared__ float c1[D];
    __shared__ float part[8][33];
    __shared__ int cnts[128];
    c1[t]       = fmaxf(b1[t], 0.f);
    c1[t + 256] = fmaxf(b1[t + 256], 0.f);
    if (t < 128) {                                 // counts from pcnt
        int c = 0;
#pragma unroll
        for (int q = 0; q < 8; ++q) c += pcnt[((t >> 4) * 8 + q) * R + (t & 15)];
        cnts[t] = c;
    }
    __syncthreads();
    const int dl = t & 31, kg = t >> 5;            // 8 k-groups x 64 k
    const int d = blockIdx.x * 32 + dl;
    float p = 0.f;
    for (int k = kg * 64; k < kg * 64 + 64; ++k)
        p += c1[k] * w2[(size_t)k * D + d];
    part[kg][dl] = p;
    __syncthreads();
    if (t < 32) {
        const int dd = blockIdx.x * 32 + t;
        float acc = b2[dd];
#pragma unroll
        for (int kk = 0; kk < 8; ++kk) acc += part[kk][t];
        const float c2d = fmaxf(acc, 0.f);
        for (int br = 0; br < B * R; ++br)
            regvec[(size_t)br * D + dd] = (cnts[br] < S) ? c2d : 0.f;
    }
}

// ================= MFMA GEMM: 128x128 tile, 4 waves, 16x16x32 bf16 ==========
struct GemmCtx {
    int row0, col0, wave, lane, wr, wc;
    unsigned dsto[2];
    const ushort *aSrc[2], *bSrc[2];
    unsigned aOff[4], bOff[4];
};

__device__ __forceinline__ void gemm_setup(
    GemmCtx& c, const ushort* Ab, const ushort* Bt)
{
    const int tid = threadIdx.x;
    c.wave = tid >> 6; c.lane = tid & 63;
    c.wr = c.wave >> 1; c.wc = c.wave & 1;
    // bijective XCD swizzle over nwg=1024 (8 XCDs x 128 chunks)
    const int orig = blockIdx.x;
    const int wg = (orig & 7) * 128 + (orig >> 3);
    c.row0 = (wg >> 2) * 128;   // 256 mtiles
    c.col0 = (wg & 3) * 128;    // 4 ntiles
#pragma unroll
    for (int q = 0; q < 2; ++q) {
        const unsigned o = (unsigned)(c.wave * 2 + q) * 1024u + (unsigned)c.lane * 16u;
        c.dsto[q] = (unsigned)(c.wave * 2 + q) * 1024u;
        const unsigned r  = ((o >> 7) << 1) | (((o >> 6) ^ (o >> 8)) & 1u);
        const unsigned kg = ((o >> 4) & 3u) ^ (r & 3u);
        c.aSrc[q] = Ab + (size_t)(c.row0 + r) * D + kg * 8;
        c.bSrc[q] = Bt + (size_t)(c.col0 + r) * D + kg * 8;
    }
#pragma unroll
    for (int i = 0; i < 4; ++i) {
        const unsigned kg = (unsigned)(c.lane >> 4);
        unsigned r = (unsigned)(c.wr * 64 + i * 16 + (c.lane & 15));
        c.aOff[i] = ((r << 6) + (kg << 4)) ^ ((r & 7u) << 4);
        r = (unsigned)(c.wc * 64 + i * 16 + (c.lane & 15));
        c.bOff[i] = ((r << 6) + (kg << 4)) ^ ((r & 7u) << 4);
    }
}

#define STAGE4(ctx, smA, smB, bufofs, kt)                                 \
    gload_lds16(ctx.aSrc[0] + (kt), smA + (bufofs) + ctx.dsto[0]);        \
    gload_lds16(ctx.aSrc[1] + (kt), smA + (bufofs) + ctx.dsto[1]);        \
    gload_lds16(ctx.bSrc[0] + (kt), smB + (bufofs) + ctx.dsto[0]);        \
    gload_lds16(ctx.bSrc[1] + (kt), smB + (bufofs) + ctx.dsto[1]);

#define GEMM_KLOOP(smA, smB, ctx, acc)                                         \
    STAGE4(ctx, smA, smB, 0, 0)                                                \
    __syncthreads();                                                           \
    _Pragma("unroll")                                                          \
    for (int t = 0; t < 16; ++t) {                                             \
        const int co = (t & 1) * 8192;                                         \
        if (t < 15) { STAGE4(ctx, smA, smB, co ^ 8192, (t + 1) * 32) }         \
        short8 a[4], b[4];                                                     \
        _Pragma("unroll")                                                      \
        for (int i = 0; i < 4; ++i)                                            \
            a[i] = *(const short8*)(smA + co + ctx.aOff[i]);                   \
        _Pragma("unroll")                                                      \
        for (int j = 0; j < 4; ++j)                                            \
            b[j] = *(const short8*)(smB + co + ctx.bOff[j]);                   \
        _Pragma("unroll")                                                      \
        for (int i = 0; i < 4; ++i)                                            \
            _Pragma("unroll")                                                  \
            for (int j = 0; j < 4; ++j)                                        \
                acc[i][j] = __builtin_amdgcn_mfma_f32_16x16x32_bf16(           \
                    a[i], b[j], acc[i][j], 0, 0, 0);                           \
        __syncthreads();                                                       \
    }

// GEMM1: h1 = relu(xb @ w1t^T + b1), bf16 out.  (256,3): cap VGPR at ~170 so
// 3 blocks/CU fit (LDS 32KB allows it) — m114: wave-level overlap needs ~3.
__global__ __launch_bounds__(256, 3) void gemm_mfma1(
    const ushort* __restrict__ Ab, const ushort* __restrict__ Bt,
    const float* __restrict__ bias, ushort* __restrict__ H)
{
    __shared__ ushort As[8192];
    __shared__ ushort Bs[8192];
    GemmCtx c; gemm_setup(c, Ab, Bt);
    char* smA = (char*)As; char* smB = (char*)Bs;
    f32x4 acc[4][4];
#pragma unroll
    for (int i = 0; i < 4; ++i)
#pragma unroll
        for (int j = 0; j < 4; ++j) acc[i][j] = (f32x4)0.f;
    GEMM_KLOOP(smA, smB, c, acc)
    float bb[4];
#pragma unroll
    for (int j = 0; j < 4; ++j) bb[j] = bias[c.col0 + c.wc * 64 + j * 16 + (c.lane & 15)];
#pragma unroll
    for (int i = 0; i < 4; ++i) {
        const int row = c.row0 + c.wr * 64 + i * 16 + ((c.lane >> 4) << 2);
#pragma unroll
        for (int j = 0; j < 4; ++j) {
            const int col = c.col0 + c.wc * 64 + j * 16 + (c.lane & 15);
#pragma unroll
            for (int ii = 0; ii < 4; ++ii) {
                const float v = fmaxf(acc[i][j][ii] + bb[j], 0.f);
                H[(size_t)(row + ii) * D + col] = f2bf(v);
            }
        }
    }
}

// GEMM2: v = relu(h1 @ w2t^T + b2); segmented max by reg_indx into regvec
__global__ __launch_bounds__(256, 3) void gemm_mfma2(
    const ushort* __restrict__ Ab, const ushort* __restrict__ Bt,
    const float* __restrict__ bias, const int* __restrict__ reg_indx,
    float* __restrict__ regvec)
{
    __shared__ ushort As[8192];
    __shared__ ushort Bs[8192];
    __shared__ unsigned redmax[R * 128];
    __shared__ int rowreg[128];
    GemmCtx c; gemm_setup(c, Ab, Bt);
    char* smA = (char*)As; char* smB = (char*)Bs;
    const int tid = threadIdx.x;
    if (tid < 128) rowreg[tid] = reg_indx[c.row0 + tid];
#pragma unroll
    for (int q = 0; q < 8; ++q) redmax[tid + q * 256] = 0u;
    f32x4 acc[4][4];
#pragma unroll
    for (int i = 0; i < 4; ++i)
#pragma unroll
        for (int j = 0; j < 4; ++j) acc[i][j] = (f32x4)0.f;
    GEMM_KLOOP(smA, smB, c, acc)   // barriers inside make the init visible
    float bb[4];
#pragma unroll
    for (int j = 0; j < 4; ++j) bb[j] = bias[c.col0 + c.wc * 64 + j * 16 + (c.lane & 15)];
#pragma unroll
    for (int i = 0; i < 4; ++i) {
        const int lrow = c.wr * 64 + i * 16 + ((c.lane >> 4) << 2);
#pragma unroll
        for (int j = 0; j < 4; ++j) {
            const int lcol = c.wc * 64 + j * 16 + (c.lane & 15);
#pragma unroll
            for (int ii = 0; ii < 4; ++ii) {
                const float v = fmaxf(acc[i][j][ii] + bb[j], 0.f);
                atomicMax(&redmax[rowreg[lrow + ii] * 128 + lcol], __float_as_uint(v));
            }
        }
    }
    __syncthreads();
    const int b = c.row0 >> 12;
#pragma unroll
    for (int q = 0; q < 8; ++q) {
        const int idx = tid + q * 256;
        const int r = idx >> 7, col = idx & 127;
        atomicMax((unsigned*)&regvec[(((size_t)b * R + r) << 9) + c.col0 + col],
                  redmax[idx]);
    }
}

// ---------------- output: middle slice only (x/g written by occ) ------------
__global__ __launch_bounds__(256) void out_mid_kernel(
    const float* __restrict__ regvec, const int* __restrict__ reg_indx,
    float* __restrict__ out)
{
    const int row = blockIdx.x * 2 + (threadIdx.x >> 7);
    const int t = threadIdx.x & 127;
    const int b = row >> 12;
    const int r = reg_indx[row];
    const float4* rv = (const float4*)(regvec + ((size_t)b * R + r) * D);
    float4* o = (float4*)(out + (size_t)row * 3 * D + D);
    o[t] = rv[t];
}

// ---------------- fallback full output assembly (carve path) ----------------
__global__ __launch_bounds__(256) void out_full_kernel(
    const float* __restrict__ x, const float* __restrict__ g,
    const float* __restrict__ regvec, const int* __restrict__ reg_indx,
    float* __restrict__ out)
{
    const int row = blockIdx.x * 2 + (threadIdx.x >> 7);
    const int t = threadIdx.x & 127;
    const int b = row >> 12;
    const int r = reg_indx[row];
    const float4* xr = (const float4*)(x + (size_t)row * D);
    const float4* rv = (const float4*)(regvec + ((size_t)b * R + r) * D);
    const float4* gr = (const float4*)(g + (size_t)b * D);
    float4* o = (float4*)(out + (size_t)row * 3 * D);
    o[t]       = xr[t];
    o[128 + t] = rv[t];
    o[256 + t] = gr[t];
}

extern "C" void kernel_launch(void* const* d_in, const int* in_sizes, int n_in,
                              void* d_out, int out_size, void* d_ws, size_t ws_size,
                              hipStream_t stream)
{
    (void)in_sizes; (void)n_in; (void)out_size;
    const float* x     = (const float*)d_in[0];
    const float* g_vec = (const float*)d_in[1];
    const float* occ_w = (const float*)d_in[2];
    const float* occ_b = (const float*)d_in[3];
    const float* w1    = (const float*)d_in[4];
    const float* b1    = (const float*)d_in[5];
    const float* w2    = (const float*)d_in[6];
    const float* b2    = (const float*)d_in[7];
    float* out = (float*)d_out;

    char* ws = (char*)d_ws;
    size_t off = 0;
    auto alloc = [&](size_t bytes) {
        char* p = ws + off; off = (off + bytes + 255) & ~(size_t)255; return p;
    };
    int*    reg_indx  = (int*)alloc((size_t)M * 4);
    float*  reg_logit = (float*)alloc((size_t)M * 4);
    int*    pcnt      = (int*)alloc(64 * R * 4);
    double* psum      = (double*)alloc(64 * R * 8);
    float*  regvec    = (float*)alloc((size_t)B * R * D * 4);

    const size_t xbB = (size_t)M * D * 2, wB = (size_t)D * D * 2;
    ushort *xb, *h1, *w1t, *w2t;
    int fused;                        // 1: ws holds intermediates, occ writes out.x/g
    if (ws_size >= off + 2 * xbB + 2 * wB + 1024) {
        fused = 1;
        xb  = (ushort*)alloc(xbB);
        h1  = (ushort*)alloc(xbB);
        w1t = (ushort*)alloc(wB);
        w2t = (ushort*)alloc(wB);
    } else {                          // carve from d_out; fully rewritten later
        fused = 0;
        char* o = (char*)d_out;
        xb  = (ushort*)o;
        h1  = (ushort*)(o + xbB);
        w1t = (ushort*)(o + 2 * xbB);
        w2t = (ushort*)(o + 2 * xbB + wB);
    }

    hipLaunchKernelGGL(occ_kernel, dim3(1024), dim3(256), 0, stream,
                       x, occ_w, occ_b, g_vec, reg_indx, reg_logit, xb,
                       w1, w2, w1t, w2t, out, fused);
    hipLaunchKernelGGL(loss_part_kernel, dim3(64), dim3(256), 0, stream,
                       reg_indx, reg_logit, pcnt, psum);
    hipLaunchKernelGGL(finalize_kernel, dim3(17), dim3(256), 0, stream,
                       pcnt, psum, b1, w2, b2, regvec, out + OUT_ELEMS);
    hipLaunchKernelGGL(gemm_mfma1, dim3((M / 128) * (D / 128)), dim3(256), 0, stream,
                       xb, w1t, b1, h1);
    hipLaunchKernelGGL(gemm_mfma2, dim3((M / 128) * (D / 128)), dim3(256), 0, stream,
                       h1, w2t, b2, reg_indx, regvec);
    if (fused) {
        hipLaunchKernelGGL(out_mid_kernel, dim3(M / 2), dim3(256), 0, stream,
                           regvec, reg_indx, out);
    } else {
        hipLaunchKernelGGL(out_full_kernel, dim3(M / 2), dim3(256), 0, stream,
                           x, g_vec, regvec, reg_indx, out);
    }
}